// Round 5
// baseline (573.008 us; speedup 1.0000x reference)
//
#include <hip/hip_runtime.h>
#include <hip/hip_bf16.h>
#include <cstdint>

using u16 = unsigned short;
using u32 = unsigned int;

typedef __bf16 bf16x8 __attribute__((ext_vector_type(8)));
typedef float  f32x4  __attribute__((ext_vector_type(4)));

#define DEV static __device__ __forceinline__

DEV float bf2f(u16 u){ union { u32 u; float f; } c; c.u = ((u32)u) << 16; return c.f; }

// hardware RNE f32->bf16
DEV u16 f2bf(float f){
  __bf16 h = (__bf16)f;
  return __builtin_bit_cast(u16, h);
}

DEV float fast_rcp(float x){ return __builtin_amdgcn_rcpf(x); }

DEV void async16(const u16* g, u16* l){
  __builtin_amdgcn_global_load_lds((const __attribute__((address_space(1))) u32*)g,
                                   (__attribute__((address_space(3))) u32*)l,
                                   16, 0, 0);
}

#define SB() __builtin_amdgcn_sched_barrier(0)
#define BARRIER() do { __builtin_amdgcn_s_barrier(); SB(); } while (0)
#define LGKM0() do { __asm__ volatile("s_waitcnt lgkmcnt(0)" ::: "memory"); SB(); } while (0)
#define VMCNT0() do { __asm__ volatile("s_waitcnt vmcnt(0)" ::: "memory"); SB(); } while (0)

// ---------------- fused weight transposes + f32->bf16 (one launch) ----------------
__global__ __launch_bounds__(256)
void transpose_all(const float* __restrict__ W0, const float* __restrict__ W1,
                   const float* __restrict__ W2, const float* __restrict__ W3,
                   const float* __restrict__ W4, const float* __restrict__ W5,
                   u16* __restrict__ T0, u16* __restrict__ T1, u16* __restrict__ T2,
                   u16* __restrict__ T3, u16* __restrict__ T4, u16* __restrict__ T5){
  const int z = blockIdx.z;
  const float* W; u16* WT; int R, C;
  switch (z){
    case 0:  W = W0; WT = T0; R = 512;  C = 1024; break;
    case 1:  W = W1; WT = T1; R = 512;  C = 1024; break;
    case 2:  W = W2; WT = T2; R = 512;  C = 1024; break;
    case 3:  W = W3; WT = T3; R = 1024; C = 512;  break;
    case 4:  W = W4; WT = T4; R = 512;  C = 1024; break;
    default: W = W5; WT = T5; R = 1024; C = 512;  break;
  }
  const int c0 = blockIdx.x * 32, r0 = blockIdx.y * 32;
  if (c0 >= C || r0 >= R) return;
  __shared__ float tile[32][33];
  const int tx = threadIdx.x, ty = threadIdx.y;  // (32,8)
  #pragma unroll
  for (int j = 0; j < 4; ++j)
    tile[ty + j*8][tx] = W[(size_t)(r0 + ty + j*8) * C + (c0 + tx)];
  __syncthreads();
  #pragma unroll
  for (int j = 0; j < 4; ++j)
    WT[(size_t)(c0 + ty + j*8) * R + (r0 + tx)] = f2bf(tile[tx][ty + j*8]);
}

// ---------------- LayerNorm: one wave per 512-elem row ----------------
template<bool BF16IN>
__global__ __launch_bounds__(256)
void ln_kernel(const void* __restrict__ xin, const float* __restrict__ gamma,
               const float* __restrict__ beta, u16* __restrict__ xout){
  const int wid = threadIdx.x >> 6;
  const int lane = threadIdx.x & 63;
  const size_t row = (size_t)blockIdx.x * 4 + wid;
  const int d0 = lane * 8;
  float v[8];
  if constexpr (BF16IN){
    const u16* xp = (const u16*)xin + row * 512 + d0;
    uint4 p = *(const uint4*)xp;
    const u16* s = (const u16*)&p;
    #pragma unroll
    for (int i = 0; i < 8; ++i) v[i] = bf2f(s[i]);
  } else {
    const float* xp = (const float*)xin + row * 512 + d0;
    float4 p0 = *(const float4*)xp;
    float4 p1 = *(const float4*)(xp + 4);
    v[0]=p0.x; v[1]=p0.y; v[2]=p0.z; v[3]=p0.w;
    v[4]=p1.x; v[5]=p1.y; v[6]=p1.z; v[7]=p1.w;
  }
  float s = 0.f, sq = 0.f;
  #pragma unroll
  for (int i = 0; i < 8; ++i){ s += v[i]; sq += v[i]*v[i]; }
  #pragma unroll
  for (int o = 32; o >= 1; o >>= 1){ s += __shfl_xor(s, o); sq += __shfl_xor(sq, o); }
  const float mu  = s * (1.0f/512.0f);
  const float var = sq * (1.0f/512.0f) - mu*mu;
  const float rstd = rsqrtf(var + 1e-5f);
  const float4 g0 = *(const float4*)(gamma + d0);
  const float4 g1 = *(const float4*)(gamma + d0 + 4);
  const float4 b0 = *(const float4*)(beta + d0);
  const float4 b1 = *(const float4*)(beta + d0 + 4);
  float gg[8] = {g0.x,g0.y,g0.z,g0.w,g1.x,g1.y,g1.z,g1.w};
  float bb[8] = {b0.x,b0.y,b0.z,b0.w,b1.x,b1.y,b1.z,b1.w};
  u16 o8[8];
  #pragma unroll
  for (int i = 0; i < 8; ++i)
    o8[i] = f2bf((v[i]-mu)*rstd*gg[i] + bb[i]);
  *(uint4*)(xout + row*512 + d0) = *(const uint4*)o8;
}

// ---- fused AFT: weighted[t,h] = sum_b n*v / sum_b n ; Yt[b,t,h] = Qsig[b,t,h]*weighted ----
__global__ __launch_bounds__(256)
void aft_fused(const u16* __restrict__ numer, const u16* __restrict__ V,
               const u16* __restrict__ qs, u16* __restrict__ yt){
  const size_t TH = (size_t)4096 * 1024;
  const size_t i8 = ((size_t)blockIdx.x * 256 + threadIdx.x) * 8;
  float den[8], ws[8];
  #pragma unroll
  for (int j = 0; j < 8; ++j){ den[j] = 0.f; ws[j] = 0.f; }
  #pragma unroll
  for (int b = 0; b < 8; ++b){
    uint4 pn = *(const uint4*)(numer + b*TH + i8);
    uint4 pv = *(const uint4*)(V     + b*TH + i8);
    const u16* n = (const u16*)&pn;
    const u16* v = (const u16*)&pv;
    #pragma unroll
    for (int j = 0; j < 8; ++j){ float nf = bf2f(n[j]); den[j] += nf; ws[j] += nf * bf2f(v[j]); }
  }
  float w[8];
  #pragma unroll
  for (int j = 0; j < 8; ++j) w[j] = ws[j] * fast_rcp(den[j]);
  #pragma unroll
  for (int b = 0; b < 8; ++b){
    uint4 pq = *(const uint4*)(qs + b*TH + i8);
    const u16* q = (const u16*)&pq;
    u16 o[8];
    #pragma unroll
    for (int j = 0; j < 8; ++j) o[j] = f2bf(bf2f(q[j]) * w[j]);
    *(uint4*)(yt + b*TH + i8) = *(const uint4*)o;
  }
}

// ===== 256x256 bf16 MFMA GEMM, C = A[M,K] @ Bt[N,K]^T — A in LDS (dbuf), B global->reg =====
// 8 waves (2M x 4N), per-wave 128x64 output, BK=64.
// A: double-buffered LDS (2 x 32 KiB, static 64 KiB total), staged one tile ahead via
//    global_load_lds; XOR swizzle (chunk ^= row&7) pre-applied on global source.
// B: PREFETCHED GLOBAL->VGPR one tile ahead (8 x b128/wave). B panels are 1-3 MB and
//    L2-pinned by the supergroup mapping, so these are L2 hits on the vector-mem pipe —
//    off the LDS pipe entirely. Byte-identical frags to the old LDS path.
// Sync per K-tile: ONE vmcnt(0) + ONE barrier, both waiting on loads issued a full tile
// (~2400 cyc) earlier -> latency fully hidden; LDS reads (A only) overlap MFMA backlog.
//   step(t): vmcnt(0); barrier; ds_read A(mh0); lgkm0; [issue B(t+1), stage A(t+1)];
//            32 MFMA; ds_read A(mh1); lgkm0; 32 MFMA.
// Grid: XCD-pinned supergroups of 4 M-tiles x all N-tiles (A-chunk + B panel in 4MB L2).
template<int EPI, int KC>
__global__ __launch_bounds__(512, 2)
void gemm256(const u16* __restrict__ A, const u16* __restrict__ Bt,
             const float* __restrict__ bias0, const float* __restrict__ wbias,
             u16* __restrict__ out0, u16* __restrict__ out1, u16* __restrict__ out2,
             const float* __restrict__ bias1, const float* __restrict__ bias2,
             const u16* __restrict__ resid, float* __restrict__ outf){
  constexpr int NT = KC / 64;                 // K-tiles (8 or 16, always even)
  __shared__ __align__(16) char smem[65536];  // A buf0 | A buf1, 32 KiB each (256 rows x 128 B)

  const int tid  = threadIdx.x;
  const int wid  = tid >> 6;
  const int lane = tid & 63;
  const int quad = lane >> 4;
  const int lr   = lane & 15;
  const int wm   = wid & 1;      // M-wave (2)
  const int wn   = wid >> 1;     // N-wave (4)

  // bijective XCD swizzle + L2 supergroups (4 M-tiles x all N-tiles, M fastest)
  const int nwg = gridDim.x;                 // = 128 * nNT (always % 8 == 0)
  const int wg  = (blockIdx.x & 7) * (nwg >> 3) + (blockIdx.x >> 3);
  const int nNT = nwg >> 7;                  // N-tiles: 12 / 2 / 4 / 2
  const int sgs = nNT << 2;                  // supergroup size (4*nNT)
  const int sg  = wg / sgs;
  const int r   = wg - sg * sgs;
  const int tileM = (sg*4 + (r & 3)) * 256;
  const int tileN = (r >> 2) * 256;

  // ---- A staging source (pre-swizzled global address; LDS write stays linear) ----
  // call r writes LDS bytes [wid*4096 + r*1024 + lane*16): row rr = wid*32 + r*8 + (lane>>3),
  // chunk c = lane&7; global k-chunk = c ^ (rr&7) = (lane&7) ^ (lane>>3)  (r-independent).
  const u16* pA = A + (size_t)(tileM + wid*32 + (lane >> 3)) * KC
                    + (((lane & 7) ^ (lane >> 3)) << 3);
  auto stageA = [&](char* nb, int kt){
    char* d = nb + wid*4096 + (lane << 4);
    #pragma unroll
    for (int rr = 0; rr < 4; ++rr)
      async16(pA + (size_t)rr*8*KC + kt, (u16*)(d + rr*1024));
  };

  // ---- B global->reg pointers: frag (nh,j,kc) = 16B at row (tileN+wn*64+nh*32+j*16+lr),
  //      col kt + kc*32 + quad*8 ----
  const u16* pB[2][2];
  #pragma unroll
  for (int nh = 0; nh < 2; ++nh)
    #pragma unroll
    for (int j = 0; j < 2; ++j)
      pB[nh][j] = Bt + (size_t)(tileN + wn*64 + nh*32 + j*16 + lr) * KC + quad*8;

  // ---- A fragment read offsets (row&7 == lr&7 for all frags) ----
  const int cO0 = ((quad)     ^ (lr & 7)) << 4;   // kc=0 swizzled chunk byte
  const int cO1 = ((quad ^ 4) ^ (lr & 7)) << 4;   // kc=1
  const int aRowBase = (wm*128 + lr) * 128;       // + mh*8192 + i*2048

  bf16x8 ar[4][2];
  bf16x8 brA[2][2][2], brB[2][2][2];              // [nh][j][kc], cur/next tile
  f32x4 acc[2][2][4][2] = {};                     // [mh][nh][i][j]

  auto loadB = [&](bf16x8 (&br)[2][2][2], int kt){
    #pragma unroll
    for (int nh = 0; nh < 2; ++nh)
      #pragma unroll
      for (int j = 0; j < 2; ++j){
        br[nh][j][0] = *(const bf16x8*)(pB[nh][j] + kt);
        br[nh][j][1] = *(const bf16x8*)(pB[nh][j] + kt + 32);
      }
  };
  auto ldA = [&](const char* cb, int mh){
    #pragma unroll
    for (int i = 0; i < 4; ++i){
      ar[i][0] = *(const bf16x8*)(cb + aRowBase + mh*8192 + i*2048 + cO0);
      ar[i][1] = *(const bf16x8*)(cb + aRowBase + mh*8192 + i*2048 + cO1);
    }
  };
  auto MF = [&](int mh, bf16x8 (&br)[2][2][2]){
    __builtin_amdgcn_s_setprio(1);
    #pragma unroll
    for (int i = 0; i < 4; ++i)
      #pragma unroll
      for (int nh = 0; nh < 2; ++nh)
        #pragma unroll
        for (int j = 0; j < 2; ++j){
          acc[mh][nh][i][j] = __builtin_amdgcn_mfma_f32_16x16x32_bf16(br[nh][j][0], ar[i][0], acc[mh][nh][i][j], 0, 0, 0);
          acc[mh][nh][i][j] = __builtin_amdgcn_mfma_f32_16x16x32_bf16(br[nh][j][1], ar[i][1], acc[mh][nh][i][j], 0, 0, 0);
        }
    __builtin_amdgcn_s_setprio(0);
  };

  // ---- prologue: issue tile0 loads (only exposed-latency wait of the WG) ----
  loadB(brA, 0);
  stageA(smem, 0);

  auto step = [&](const char* cb, char* nb,
                  bf16x8 (&brCur)[2][2][2], bf16x8 (&brNxt)[2][2][2], int t){
    VMCNT0();                 // A(t) staged + B(t) regs landed (issued a full tile ago)
    BARRIER();
    ldA(cb, 0);
    LGKM0();
    if (t + 1 < NT){ loadB(brNxt, (t+1)*64); stageA(nb, (t+1)*64); }
    MF(0, brCur);
    ldA(cb, 1);
    LGKM0();
    MF(1, brCur);
  };

  #pragma unroll 1
  for (int t = 0; t < NT; t += 2){
    step(smem,         smem + 32768, brA, brB, t);
    step(smem + 32768, smem,         brB, brA, t + 1);
  }

  // ---- epilogue ----
  // acc[mh][nh][i][j][r] = C[tileM + wm*128 + mh*64 + i*16 + lr]
  //                         [tileN + wn*64 + nh*32 + j*16 + quad*4 + r]
  if (EPI == 3){
    #pragma unroll
    for (int mh = 0; mh < 2; ++mh)
    #pragma unroll
    for (int i = 0; i < 4; ++i){
      const int row = tileM + wm*128 + mh*64 + i*16 + lr;
      #pragma unroll
      for (int nh = 0; nh < 2; ++nh)
      #pragma unroll
      for (int j = 0; j < 2; ++j){
        const int colb = tileN + wn*64 + nh*32 + j*16 + quad*4;
        const float4 bvv = *(const float4*)(bias0 + colb);
        float4 o;
        #pragma unroll
        for (int r_ = 0; r_ < 4; ++r_)
          ((float*)&o)[r_] = 2.0f * (acc[mh][nh][i][j][r_] + ((const float*)&bvv)[r_]);
        *(float4*)(outf + (size_t)row * 512 + colb) = o;
      }
    }
    return;
  }

  // bf16 epilogues with per-wave LDS bounce -> full 128-B-line global stores.
  // Bounce region lives in buf0; all cross-wave reads of buf0 drained before the
  // final step's barrier, and the region is wave-private with per-wave lgkm waits.
  char* eb = smem + wid * 2304;              // 16 rows x 144 B
  const int mat = (EPI == 0) ? (tileN >> 10) : 0;   // 0:Q 1:K 2:V
  const float* biasP = bias0;
  u16* outP = out0;
  int ldO = 1024, cb0 = tileN + wn*64;
  if (EPI == 0){
    biasP = (mat==0) ? bias0 : (mat==1) ? bias1 : bias2;
    outP  = (mat==0) ? out0  : (mat==1) ? out1  : out2;
    cb0   = (tileN & 1023) + wn*64;
  } else if (EPI == 1){
    ldO = 512;
  }

  #pragma unroll
  for (int mh = 0; mh < 2; ++mh)
  #pragma unroll
  for (int i = 0; i < 4; ++i){
    const int row = tileM + wm*128 + mh*64 + i*16 + lr;
    #pragma unroll
    for (int nh = 0; nh < 2; ++nh)
    #pragma unroll
    for (int j = 0; j < 2; ++j){
      const int cl = (nh*2 + j)*16 + quad*4;
      const float4 bvv = *(const float4*)(biasP + cb0 + cl);
      u16 o[4];
      if (EPI == 0){
        float4 wbv = {0,0,0,0};
        if (mat == 1) wbv = *(const float4*)(wbias + cb0 + cl);
        #pragma unroll
        for (int r_ = 0; r_ < 4; ++r_){
          float v = acc[mh][nh][i][j][r_] + ((const float*)&bvv)[r_];
          if (mat == 0)      v = fast_rcp(1.0f + __expf(-v));
          else if (mat == 1) v = __expf(v + ((const float*)&wbv)[r_]);
          o[r_] = f2bf(v);
        }
      } else if (EPI == 1){
        uint2 pr = *(const uint2*)(resid + (size_t)row * 512 + cb0 + cl);
        const u16* rp = (const u16*)&pr;
        #pragma unroll
        for (int r_ = 0; r_ < 4; ++r_)
          o[r_] = f2bf(acc[mh][nh][i][j][r_] + ((const float*)&bvv)[r_] + bf2f(rp[r_]));
      } else {
        #pragma unroll
        for (int r_ = 0; r_ < 4; ++r_){
          float v  = acc[mh][nh][i][j][r_] + ((const float*)&bvv)[r_];
          float u2 = 2.0f * v * (0.7978845608f + 0.0356774081f * v * v);
          float tg = 1.0f - 2.0f * fast_rcp(1.0f + __expf(u2));
          o[r_] = f2bf(0.5f * v * (1.0f + tg));
        }
      }
      *(uint2*)(eb + lr*144 + cl*2) = *(const uint2*)o;
    }
    __asm__ volatile("s_waitcnt lgkmcnt(0)" ::: "memory");
    uint4 p0 = *(const uint4*)(eb + lr*144 + quad*32);
    uint4 p1 = *(const uint4*)(eb + lr*144 + quad*32 + 16);
    __asm__ volatile("s_waitcnt lgkmcnt(0)" ::: "memory");
    u16* gp = outP + (size_t)row * ldO + cb0 + quad*16;
    *(uint4*)gp = p0;
    *(uint4*)(gp + 8) = p1;
  }
}

extern "C" void kernel_launch(void* const* d_in, const int* in_sizes, int n_in,
                              void* d_out, int out_size, void* d_ws, size_t ws_size,
                              hipStream_t stream) {
  const float* x     = (const float*)d_in[0];
  const float* gamma = (const float*)d_in[1];
  const float* beta  = (const float*)d_in[2];
  const float* Wq    = (const float*)d_in[3];
  const float* bq    = (const float*)d_in[4];
  const float* Wk    = (const float*)d_in[5];
  const float* bk    = (const float*)d_in[6];
  const float* Wv    = (const float*)d_in[7];
  const float* bv    = (const float*)d_in[8];
  const float* wbias = (const float*)d_in[9];
  const float* Wo    = (const float*)d_in[10];
  const float* bo    = (const float*)d_in[11];
  const float* W1    = (const float*)d_in[12];
  const float* b1    = (const float*)d_in[13];
  const float* W2    = (const float*)d_in[14];
  const float* b2    = (const float*)d_in[15];
  float* out = (float*)d_out;

  char* w = (char*)d_ws;
  const size_t MB = 1ull << 20;
  u16* WqkvT = (u16*)(w + 0*MB);      // [3072][512]  (WqT | WkT | WvT)
  u16* WoT   = (u16*)(w + 3*MB);      // [512][1024]
  u16* W1T   = (u16*)(w + 4*MB);      // [1024][512]
  u16* W2T   = (u16*)(w + 5*MB);      // [512][1024]
  u16* x1b   = (u16*)(w + 6*MB);      // [32768][512]
  u16* Qs    = (u16*)(w + 38*MB);     // [32768][1024]
  u16* Nu    = (u16*)(w + 102*MB);    // [32768][1024]
  u16* Vb    = (u16*)(w + 166*MB);    // [32768][1024]
  u16* Yt    = Nu;                    // in-place over numer
  u16* x2b   = Vb;                    // reuse (V consumed by aft_fused)
  u16* x3b   = (u16*)(w + 198*MB);
  u16* hb    = Qs;                    // reuse (Qsig consumed by aft_fused)

  transpose_all<<<dim3(32, 32, 6), dim3(32, 8), 0, stream>>>(
      Wq, Wk, Wv, Wo, W1, W2,
      WqkvT, WqkvT + 1024*512, WqkvT + 2*1024*512, WoT, W1T, W2T);

  ln_kernel<false><<<8192, 256, 0, stream>>>(x, gamma, beta, x1b);

  // QKV: [32768,512] @ [3072,512]^T ; 128 M-tiles x 12 N-tiles
  gemm256<0, 512><<<1536, 512, 0, stream>>>(x1b, WqkvT,
      bq, wbias, Qs, Nu, Vb, bk, bv, nullptr, nullptr);

  aft_fused<<<2048, 256, 0, stream>>>(Nu, Vb, Qs, Yt);

  // attn out: [32768,1024] @ [512,1024]^T ; 128 x 2
  gemm256<1, 1024><<<256, 512, 0, stream>>>(Yt, WoT,
      bo, nullptr, x2b, nullptr, nullptr, nullptr, nullptr, x1b, nullptr);

  ln_kernel<true><<<8192, 256, 0, stream>>>(x2b, gamma, beta, x3b);

  // mlp1: [32768,512] @ [1024,512]^T ; 128 x 4
  gemm256<2, 512><<<512, 512, 0, stream>>>(x3b, W1T,
      b1, nullptr, hb, nullptr, nullptr, nullptr, nullptr, nullptr, nullptr);

  // mlp2: [32768,1024] @ [512,1024]^T ; 128 x 2
  gemm256<3, 1024><<<256, 512, 0, stream>>>(hb, W2T,
      b2, nullptr, nullptr, nullptr, nullptr, nullptr, nullptr, nullptr, out);
}

// Round 7
// 485.009 us; speedup vs baseline: 1.1814x; 1.1814x over previous
//
#include <hip/hip_runtime.h>
#include <hip/hip_bf16.h>
#include <cstdint>

using u16 = unsigned short;
using u32 = unsigned int;

typedef __bf16 bf16x8 __attribute__((ext_vector_type(8)));
typedef float  f32x4  __attribute__((ext_vector_type(4)));

#define DEV static __device__ __forceinline__

DEV float bf2f(u16 u){ union { u32 u; float f; } c; c.u = ((u32)u) << 16; return c.f; }

// hardware RNE f32->bf16
DEV u16 f2bf(float f){
  __bf16 h = (__bf16)f;
  return __builtin_bit_cast(u16, h);
}

DEV float fast_rcp(float x){ return __builtin_amdgcn_rcpf(x); }

DEV void async16(const u16* g, u16* l){
  __builtin_amdgcn_global_load_lds((const __attribute__((address_space(1))) u32*)g,
                                   (__attribute__((address_space(3))) u32*)l,
                                   16, 0, 0);
}

#define SB() __builtin_amdgcn_sched_barrier(0)
#define BARRIER() do { __builtin_amdgcn_s_barrier(); SB(); } while (0)
#define LGKM0() do { __asm__ volatile("s_waitcnt lgkmcnt(0)" ::: "memory"); SB(); } while (0)
#define VMCNT(n) __asm__ volatile("s_waitcnt vmcnt(" #n ")" ::: "memory")

// ---------------- weight pack: transpose + f32->bf16 + FRAGMENT-MAJOR B layout ----------------
// Bf layout per weight (K=R rows, N=C cols), NKT = K/64:
//   chunk (n, k0..k0+7) stored at u16 offset
//     ((nt*NKT + ki)*4 + wn)*4096 + f*512 + (quad*16 + lr)*8
//   nt=n>>8, wn=(n>>6)&3, nh=(n>>5)&1, jj=(n>>4)&1, lr=n&15,
//   ki=k0>>6, ks=(k0>>5)&1, quad=(k0>>3)&3, f=(nh*2+jj)*2+ks.
// Each wave's 8 B-fragment loads per K-tile are then contiguous 1KB dwordx4 (coalesced).
__global__ __launch_bounds__(256)
void transpose_all(const float* __restrict__ W0, const float* __restrict__ W1,
                   const float* __restrict__ W2, const float* __restrict__ W3,
                   const float* __restrict__ W4, const float* __restrict__ W5,
                   u16* __restrict__ T0, u16* __restrict__ T1, u16* __restrict__ T2,
                   u16* __restrict__ T3, u16* __restrict__ T4, u16* __restrict__ T5){
  const int z = blockIdx.z;
  const float* W; u16* WT; int R, C;
  switch (z){
    case 0:  W = W0; WT = T0; R = 512;  C = 1024; break;
    case 1:  W = W1; WT = T1; R = 512;  C = 1024; break;
    case 2:  W = W2; WT = T2; R = 512;  C = 1024; break;
    case 3:  W = W3; WT = T3; R = 1024; C = 512;  break;
    case 4:  W = W4; WT = T4; R = 512;  C = 1024; break;
    default: W = W5; WT = T5; R = 1024; C = 512;  break;
  }
  const int c0 = blockIdx.x * 32, r0 = blockIdx.y * 32;   // r = K dim, c = N dim
  if (c0 >= C || r0 >= R) return;
  __shared__ float tile[32][33];                           // tile[k][n]
  const int tx = threadIdx.x, ty = threadIdx.y;            // (32,8)
  #pragma unroll
  for (int j = 0; j < 4; ++j)
    tile[ty + j*8][tx] = W[(size_t)(r0 + ty + j*8) * C + (c0 + tx)];
  __syncthreads();
  if (ty < 4){
    const int n  = c0 + tx;
    const int k0 = r0 + ty*8;
    u16 ch[8];
    #pragma unroll
    for (int i = 0; i < 8; ++i) ch[i] = f2bf(tile[ty*8 + i][tx]);
    const int NKT = R >> 6;
    const int nt = n >> 8, np = n & 255;
    const int wn = np >> 6, nh = (np >> 5) & 1, jj = (np >> 4) & 1, lr = np & 15;
    const int ki = k0 >> 6, kp = k0 & 63, ks = kp >> 5, qd = (kp >> 3) & 3;
    const int f  = (nh*2 + jj)*2 + ks;
    const size_t off = (size_t)((nt*NKT + ki)*4 + wn)*4096 + f*512 + (qd*16 + lr)*8;
    *(uint4*)(WT + off) = *(const uint4*)ch;
  }
}

// ---------------- LayerNorm: one wave per 512-elem row ----------------
template<bool BF16IN>
__global__ __launch_bounds__(256)
void ln_kernel(const void* __restrict__ xin, const float* __restrict__ gamma,
               const float* __restrict__ beta, u16* __restrict__ xout){
  const int wid = threadIdx.x >> 6;
  const int lane = threadIdx.x & 63;
  const size_t row = (size_t)blockIdx.x * 4 + wid;
  const int d0 = lane * 8;
  float v[8];
  if constexpr (BF16IN){
    const u16* xp = (const u16*)xin + row * 512 + d0;
    uint4 p = *(const uint4*)xp;
    const u16* s = (const u16*)&p;
    #pragma unroll
    for (int i = 0; i < 8; ++i) v[i] = bf2f(s[i]);
  } else {
    const float* xp = (const float*)xin + row * 512 + d0;
    float4 p0 = *(const float4*)xp;
    float4 p1 = *(const float4*)(xp + 4);
    v[0]=p0.x; v[1]=p0.y; v[2]=p0.z; v[3]=p0.w;
    v[4]=p1.x; v[5]=p1.y; v[6]=p1.z; v[7]=p1.w;
  }
  float s = 0.f, sq = 0.f;
  #pragma unroll
  for (int i = 0; i < 8; ++i){ s += v[i]; sq += v[i]*v[i]; }
  #pragma unroll
  for (int o = 32; o >= 1; o >>= 1){ s += __shfl_xor(s, o); sq += __shfl_xor(sq, o); }
  const float mu  = s * (1.0f/512.0f);
  const float var = sq * (1.0f/512.0f) - mu*mu;
  const float rstd = rsqrtf(var + 1e-5f);
  const float4 g0 = *(const float4*)(gamma + d0);
  const float4 g1 = *(const float4*)(gamma + d0 + 4);
  const float4 b0 = *(const float4*)(beta + d0);
  const float4 b1 = *(const float4*)(beta + d0 + 4);
  float gg[8] = {g0.x,g0.y,g0.z,g0.w,g1.x,g1.y,g1.z,g1.w};
  float bb[8] = {b0.x,b0.y,b0.z,b0.w,b1.x,b1.y,b1.z,b1.w};
  u16 o8[8];
  #pragma unroll
  for (int i = 0; i < 8; ++i)
    o8[i] = f2bf((v[i]-mu)*rstd*gg[i] + bb[i]);
  *(uint4*)(xout + row*512 + d0) = *(const uint4*)o8;
}

// ---- fused AFT: weighted[t,h] = sum_b n*v / sum_b n ; Yt[b,t,h] = Qsig[b,t,h]*weighted ----
__global__ __launch_bounds__(256)
void aft_fused(const u16* __restrict__ numer, const u16* __restrict__ V,
               const u16* __restrict__ qs, u16* __restrict__ yt){
  const size_t TH = (size_t)4096 * 1024;
  const size_t i8 = ((size_t)blockIdx.x * 256 + threadIdx.x) * 8;
  float den[8], ws[8];
  #pragma unroll
  for (int j = 0; j < 8; ++j){ den[j] = 0.f; ws[j] = 0.f; }
  #pragma unroll
  for (int b = 0; b < 8; ++b){
    uint4 pn = *(const uint4*)(numer + b*TH + i8);
    uint4 pv = *(const uint4*)(V     + b*TH + i8);
    const u16* n = (const u16*)&pn;
    const u16* v = (const u16*)&pv;
    #pragma unroll
    for (int j = 0; j < 8; ++j){ float nf = bf2f(n[j]); den[j] += nf; ws[j] += nf * bf2f(v[j]); }
  }
  float w[8];
  #pragma unroll
  for (int j = 0; j < 8; ++j) w[j] = ws[j] * fast_rcp(den[j]);
  #pragma unroll
  for (int b = 0; b < 8; ++b){
    uint4 pq = *(const uint4*)(qs + b*TH + i8);
    const u16* q = (const u16*)&pq;
    u16 o[8];
    #pragma unroll
    for (int j = 0; j < 8; ++j) o[j] = f2bf(bf2f(q[j]) * w[j]);
    *(uint4*)(yt + b*TH + i8) = *(const uint4*)o;
  }
}

// ===== 256x256 bf16 MFMA GEMM — A double-buffered in 64KB static LDS, B global->reg =====
// 8 waves (2M x 4N), per-wave 128x64 output, BK=64.
// A: 2 x 32 KiB LDS buffers (static), staged one FULL tile ahead via global_load_lds
//    (4 instr/wave); XOR swizzle (chunk ^= row&7) pre-applied on global source.
// B: fragment-major Bf layout (see transpose_all) -> 8 coalesced dwordx4/wave/tile,
//    prefetched one full tile ahead into a second register set. Panels are L2-pinned
//    by the supergroup mapping; loads are 1-line each (R5's 16-line flaw fixed).
// LDS traffic/tile: 128KB read + 32KB write (was 192+64) -> LDS pipe off critical path.
// Sync per tile: ONE vmcnt(0) + ONE barrier; all 12 vm-ops issued a full tile (~1500cyc)
// before the wait -> latency hidden. lgkmcnt(0)+sched_barrier before each MFMA cluster;
// setprio around MFMA. Grid: XCD-pinned supergroups of 4 M-tiles x all N-tiles.
template<int EPI, int KC>
__global__ __launch_bounds__(512, 2)
void gemm256(const u16* __restrict__ A, const u16* __restrict__ Bf,
             const float* __restrict__ bias0, const float* __restrict__ wbias,
             u16* __restrict__ out0, u16* __restrict__ out1, u16* __restrict__ out2,
             const float* __restrict__ bias1, const float* __restrict__ bias2,
             const u16* __restrict__ resid, float* __restrict__ outf){
  constexpr int NT = KC / 64;                 // K-tiles (8 or 16, always even)
  __shared__ __align__(16) char smem[65536];  // A buf0 | A buf1 (256 rows x 128 B each)

  const int tid  = threadIdx.x;
  const int wid  = tid >> 6;
  const int lane = tid & 63;
  const int quad = lane >> 4;
  const int lr   = lane & 15;
  const int wm   = wid & 1;      // M-wave (2)
  const int wn   = wid >> 1;     // N-wave (4)

  // bijective XCD swizzle + L2 supergroups (4 M-tiles x all N-tiles, M fastest)
  const int nwg = gridDim.x;                 // = 128 * nNT (always % 8 == 0)
  const int wg  = (blockIdx.x & 7) * (nwg >> 3) + (blockIdx.x >> 3);
  const int nNT = nwg >> 7;                  // N-tiles: 12 / 2 / 4 / 2
  const int sgs = nNT << 2;                  // supergroup size (4*nNT)
  const int sg  = wg / sgs;
  const int r   = wg - sg * sgs;
  const int tileM = (sg*4 + (r & 3)) * 256;
  const int tileN = (r >> 2) * 256;

  // ---- A staging source (pre-swizzled; LDS dest linear) ----
  // call c writes LDS bytes c*8192 + tid*16: row rr = c*64 + (tid>>3), chunk = tid&7,
  // global k-chunk = (tid&7) ^ (rr&7) = (tid&7) ^ ((tid>>3)&7)   (c-independent).
  const u16* pA = A + (size_t)(tileM + (tid >> 3)) * KC
                    + (((tid & 7) ^ ((tid >> 3) & 7)) << 3);
  auto stageA = [&](char* nb, int kt){
    char* d = nb + tid*16;
    #pragma unroll
    for (int c = 0; c < 4; ++c)
      async16(pA + (size_t)c*64*KC + kt, (u16*)(d + c*8192));
  };

  // ---- B fragment base: per (nt, ki, wn) block of 4096 u16; lane-contiguous ----
  const u16* pB0 = Bf + (size_t)(tileN >> 8) * NT * 16384 + wn*4096 + lane*8;

  // ---- A fragment read offsets (row&7 == lr&7 for all frags) ----
  const int cO0 = ((quad)     ^ (lr & 7)) << 4;   // ks=0 swizzled chunk byte
  const int cO1 = ((quad ^ 4) ^ (lr & 7)) << 4;   // ks=1
  const int aBase = (wm*128 + lr) * 128;          // + mh*8192 + i*2048

  bf16x8 ar[4][2];
  bf16x8 brA_[2][2][2], brB_[2][2][2];            // [nh][jj][ks], cur/next tile
  f32x4 acc[2][2][4][2] = {};                     // [mh][nh][i][jj]

  auto loadB = [&](bf16x8 (&br)[2][2][2], int ki){
    const u16* b = pB0 + (size_t)ki*16384;
    #pragma unroll
    for (int nh = 0; nh < 2; ++nh)
      #pragma unroll
      for (int jj = 0; jj < 2; ++jj)
        #pragma unroll
        for (int ks = 0; ks < 2; ++ks)
          br[nh][jj][ks] = *(const bf16x8*)(b + (((nh*2+jj)*2 + ks) * 512));
  };
  auto ldA = [&](const char* cb, int mh){
    #pragma unroll
    for (int i = 0; i < 4; ++i){
      ar[i][0] = *(const bf16x8*)(cb + aBase + mh*8192 + i*2048 + cO0);
      ar[i][1] = *(const bf16x8*)(cb + aBase + mh*8192 + i*2048 + cO1);
    }
  };
  auto MF = [&](int mh, bf16x8 (&br)[2][2][2]){
    __builtin_amdgcn_s_setprio(1);
    #pragma unroll
    for (int i = 0; i < 4; ++i)
      #pragma unroll
      for (int nh = 0; nh < 2; ++nh)
        #pragma unroll
        for (int jj = 0; jj < 2; ++jj){
          acc[mh][nh][i][jj] = __builtin_amdgcn_mfma_f32_16x16x32_bf16(br[nh][jj][0], ar[i][0], acc[mh][nh][i][jj], 0, 0, 0);
          acc[mh][nh][i][jj] = __builtin_amdgcn_mfma_f32_16x16x32_bf16(br[nh][jj][1], ar[i][1], acc[mh][nh][i][jj], 0, 0, 0);
        }
    __builtin_amdgcn_s_setprio(0);
  };

  // ---- prologue: tile0 loads (the only exposed wait) ----
  stageA(smem, 0); loadB(brA_, 0);
  VMCNT(0);
  BARRIER();

  auto step = [&](const char* cb, char* nb,
                  bf16x8 (&bc)[2][2][2], bf16x8 (&bn)[2][2][2], int t){
    if (t + 1 < NT){ stageA(nb, (t+1)*64); loadB(bn, t+1); }
    ldA(cb, 0); LGKM0();
    MF(0, bc);
    ldA(cb, 1); LGKM0();
    MF(1, bc);
    if (t + 1 < NT){ VMCNT(0); BARRIER(); }
  };

  #pragma unroll 1
  for (int t = 0; t < NT; t += 2){
    step(smem,         smem + 32768, brA_, brB_, t);
    step(smem + 32768, smem,         brB_, brA_, t + 1);
  }

  // ---- epilogue ----
  // acc[mh][nh][i][jj][r] = C[tileM + wm*128 + mh*64 + i*16 + lr]
  //                          [tileN + wn*64 + nh*32 + jj*16 + quad*4 + r]
  if (EPI == 3){
    #pragma unroll
    for (int mh = 0; mh < 2; ++mh)
    #pragma unroll
    for (int i = 0; i < 4; ++i){
      const int row = tileM + wm*128 + mh*64 + i*16 + lr;
      #pragma unroll
      for (int nh = 0; nh < 2; ++nh)
      #pragma unroll
      for (int jj = 0; jj < 2; ++jj){
        const int colb = tileN + wn*64 + nh*32 + jj*16 + quad*4;
        const float4 bvv = *(const float4*)(bias0 + colb);
        float4 o;
        #pragma unroll
        for (int r_ = 0; r_ < 4; ++r_)
          ((float*)&o)[r_] = 2.0f * (acc[mh][nh][i][jj][r_] + ((const float*)&bvv)[r_]);
        *(float4*)(outf + (size_t)row * 512 + colb) = o;
      }
    }
    return;
  }

  // bf16 epilogues with per-wave LDS bounce -> full 128-B-line global stores.
  // eb lives in buf0 (bytes 0..18K); last tile (odd) read buf1, and buf0's reads
  // drained before the end-of-tile-(NT-2) barrier -> no extra barrier needed.
  char* eb = smem + wid * 2304;              // 16 rows x 144 B
  const int mat = (EPI == 0) ? (tileN >> 10) : 0;   // 0:Q 1:K 2:V
  const float* biasP = bias0;
  u16* outP = out0;
  int ldO = 1024, cb0 = tileN + wn*64;
  if (EPI == 0){
    biasP = (mat==0) ? bias0 : (mat==1) ? bias1 : bias2;
    outP  = (mat==0) ? out0  : (mat==1) ? out1  : out2;
    cb0   = (tileN & 1023) + wn*64;
  } else if (EPI == 1){
    ldO = 512;
  }

  #pragma unroll
  for (int mh = 0; mh < 2; ++mh)
  #pragma unroll
  for (int i = 0; i < 4; ++i){
    const int row = tileM + wm*128 + mh*64 + i*16 + lr;
    #pragma unroll
    for (int nh = 0; nh < 2; ++nh)
    #pragma unroll
    for (int jj = 0; jj < 2; ++jj){
      const int cl = (nh*2 + jj)*16 + quad*4;
      const float4 bvv = *(const float4*)(biasP + cb0 + cl);
      u16 o[4];
      if (EPI == 0){
        float4 wbv = {0,0,0,0};
        if (mat == 1) wbv = *(const float4*)(wbias + cb0 + cl);
        #pragma unroll
        for (int r_ = 0; r_ < 4; ++r_){
          float v = acc[mh][nh][i][jj][r_] + ((const float*)&bvv)[r_];
          if (mat == 0)      v = fast_rcp(1.0f + __expf(-v));
          else if (mat == 1) v = __expf(v + ((const float*)&wbv)[r_]);
          o[r_] = f2bf(v);
        }
      } else if (EPI == 1){
        uint2 pr = *(const uint2*)(resid + (size_t)row * 512 + cb0 + cl);
        const u16* rp = (const u16*)&pr;
        #pragma unroll
        for (int r_ = 0; r_ < 4; ++r_)
          o[r_] = f2bf(acc[mh][nh][i][jj][r_] + ((const float*)&bvv)[r_] + bf2f(rp[r_]));
      } else {
        #pragma unroll
        for (int r_ = 0; r_ < 4; ++r_){
          float v  = acc[mh][nh][i][jj][r_] + ((const float*)&bvv)[r_];
          float u2 = 2.0f * v * (0.7978845608f + 0.0356774081f * v * v);
          float tg = 1.0f - 2.0f * fast_rcp(1.0f + __expf(u2));
          o[r_] = f2bf(0.5f * v * (1.0f + tg));
        }
      }
      *(uint2*)(eb + lr*144 + cl*2) = *(const uint2*)o;
    }
    __asm__ volatile("s_waitcnt lgkmcnt(0)" ::: "memory");
    uint4 p0 = *(const uint4*)(eb + lr*144 + quad*32);
    uint4 p1 = *(const uint4*)(eb + lr*144 + quad*32 + 16);
    __asm__ volatile("s_waitcnt lgkmcnt(0)" ::: "memory");
    u16* gp = outP + (size_t)row * ldO + cb0 + quad*16;
    *(uint4*)gp = p0;
    *(uint4*)(gp + 8) = p1;
  }
}

extern "C" void kernel_launch(void* const* d_in, const int* in_sizes, int n_in,
                              void* d_out, int out_size, void* d_ws, size_t ws_size,
                              hipStream_t stream) {
  const float* x     = (const float*)d_in[0];
  const float* gamma = (const float*)d_in[1];
  const float* beta  = (const float*)d_in[2];
  const float* Wq    = (const float*)d_in[3];
  const float* bq    = (const float*)d_in[4];
  const float* Wk    = (const float*)d_in[5];
  const float* bk    = (const float*)d_in[6];
  const float* Wv    = (const float*)d_in[7];
  const float* bv    = (const float*)d_in[8];
  const float* wbias = (const float*)d_in[9];
  const float* Wo    = (const float*)d_in[10];
  const float* bo    = (const float*)d_in[11];
  const float* W1    = (const float*)d_in[12];
  const float* b1    = (const float*)d_in[13];
  const float* W2    = (const float*)d_in[14];
  const float* b2    = (const float*)d_in[15];
  float* out = (float*)d_out;

  char* w = (char*)d_ws;
  const size_t MB = 1ull << 20;
  u16* WqkvF = (u16*)(w + 0*MB);      // fragment-major: WqF|WkF|WvF (1MB each)
  u16* WoF   = (u16*)(w + 3*MB);      // 1MB
  u16* W1F   = (u16*)(w + 4*MB);      // 1MB
  u16* W2F   = (u16*)(w + 5*MB);      // 1MB
  u16* x1b   = (u16*)(w + 6*MB);      // [32768][512]
  u16* Qs    = (u16*)(w + 38*MB);     // [32768][1024]
  u16* Nu    = (u16*)(w + 102*MB);    // [32768][1024]
  u16* Vb    = (u16*)(w + 166*MB);    // [32768][1024]
  u16* Yt    = Nu;                    // in-place over numer
  u16* x2b   = Vb;                    // reuse (V consumed by aft_fused)
  u16* x3b   = (u16*)(w + 198*MB);
  u16* hb    = Qs;                    // reuse (Qsig consumed by aft_fused)

  transpose_all<<<dim3(32, 32, 6), dim3(32, 8), 0, stream>>>(
      Wq, Wk, Wv, Wo, W1, W2,
      WqkvF, WqkvF + 1024*512, WqkvF + 2*1024*512, WoF, W1F, W2F);

  ln_kernel<false><<<8192, 256, 0, stream>>>(x, gamma, beta, x1b);

  // QKV: [32768,512] @ [3072,512]^T ; 128 M-tiles x 12 N-tiles
  gemm256<0, 512><<<1536, 512, 0, stream>>>(x1b, WqkvF,
      bq, wbias, Qs, Nu, Vb, bk, bv, nullptr, nullptr);

  aft_fused<<<2048, 256, 0, stream>>>(Nu, Vb, Qs, Yt);

  // attn out: [32768,1024] @ [512,1024]^T ; 128 x 2
  gemm256<1, 1024><<<256, 512, 0, stream>>>(Yt, WoF,
      bo, nullptr, x2b, nullptr, nullptr, nullptr, nullptr, x1b, nullptr);

  ln_kernel<true><<<8192, 256, 0, stream>>>(x2b, gamma, beta, x3b);

  // mlp1: [32768,512] @ [1024,512]^T ; 128 x 4
  gemm256<2, 512><<<512, 512, 0, stream>>>(x3b, W1F,
      b1, nullptr, hb, nullptr, nullptr, nullptr, nullptr, nullptr, nullptr);

  // mlp2: [32768,1024] @ [512,1024]^T ; 128 x 2
  gemm256<3, 1024><<<256, 512, 0, stream>>>(hb, W2F,
      b2, nullptr, nullptr, nullptr, nullptr, nullptr, nullptr, nullptr, out);
}

// Round 8
// 480.565 us; speedup vs baseline: 1.1924x; 1.0092x over previous
//
#include <hip/hip_runtime.h>
#include <hip/hip_bf16.h>
#include <cstdint>

using u16 = unsigned short;
using u32 = unsigned int;

typedef __bf16 bf16x8 __attribute__((ext_vector_type(8)));
typedef float  f32x4  __attribute__((ext_vector_type(4)));

#define DEV static __device__ __forceinline__

DEV float bf2f(u16 u){ union { u32 u; float f; } c; c.u = ((u32)u) << 16; return c.f; }

// hardware RNE f32->bf16
DEV u16 f2bf(float f){
  __bf16 h = (__bf16)f;
  return __builtin_bit_cast(u16, h);
}

DEV float fast_rcp(float x){ return __builtin_amdgcn_rcpf(x); }

DEV void async16(const u16* g, u16* l){
  __builtin_amdgcn_global_load_lds((const __attribute__((address_space(1))) u32*)g,
                                   (__attribute__((address_space(3))) u32*)l,
                                   16, 0, 0);
}

#define BARRIER() __builtin_amdgcn_s_barrier()
#define LGKM0() do { __asm__ volatile("s_waitcnt lgkmcnt(0)" ::: "memory"); \
                     __builtin_amdgcn_sched_barrier(0); } while (0)
#define VMCNT(n) __asm__ volatile("s_waitcnt vmcnt(" #n ")" ::: "memory")

// ======== fused prep: 6 weight transposes (f32->bf16) + LayerNorm1, one dispatch ========
// z in [0,6): transpose; z in [6,14): LN over x (f32 in) -> x1b (bf16), 1024 blocks each z.
__global__ __launch_bounds__(256)
void prep_fused(const float* __restrict__ W0, const float* __restrict__ W1,
                const float* __restrict__ W2, const float* __restrict__ W3,
                const float* __restrict__ W4, const float* __restrict__ W5,
                u16* __restrict__ T0, u16* __restrict__ T1, u16* __restrict__ T2,
                u16* __restrict__ T3, u16* __restrict__ T4, u16* __restrict__ T5,
                const float* __restrict__ x, const float* __restrict__ gamma,
                const float* __restrict__ beta, u16* __restrict__ x1b){
  const int z = blockIdx.z;
  if (z >= 6){
    // ---- LayerNorm path: one wave per 512-elem row ----
    const int bid = (z - 6) * 1024 + blockIdx.y * 32 + blockIdx.x;
    const int tid = threadIdx.y * 32 + threadIdx.x;
    const int wid = tid >> 6;
    const int lane = tid & 63;
    const size_t row = (size_t)bid * 4 + wid;
    const int d0 = lane * 8;
    const float* xp = x + row * 512 + d0;
    float4 p0 = *(const float4*)xp;
    float4 p1 = *(const float4*)(xp + 4);
    float v[8] = {p0.x,p0.y,p0.z,p0.w,p1.x,p1.y,p1.z,p1.w};
    float s = 0.f, sq = 0.f;
    #pragma unroll
    for (int i = 0; i < 8; ++i){ s += v[i]; sq += v[i]*v[i]; }
    #pragma unroll
    for (int o = 32; o >= 1; o >>= 1){ s += __shfl_xor(s, o); sq += __shfl_xor(sq, o); }
    const float mu  = s * (1.0f/512.0f);
    const float var = sq * (1.0f/512.0f) - mu*mu;
    const float rstd = rsqrtf(var + 1e-5f);
    const float4 g0 = *(const float4*)(gamma + d0);
    const float4 g1 = *(const float4*)(gamma + d0 + 4);
    const float4 b0 = *(const float4*)(beta + d0);
    const float4 b1 = *(const float4*)(beta + d0 + 4);
    float gg[8] = {g0.x,g0.y,g0.z,g0.w,g1.x,g1.y,g1.z,g1.w};
    float bb[8] = {b0.x,b0.y,b0.z,b0.w,b1.x,b1.y,b1.z,b1.w};
    u16 o8[8];
    #pragma unroll
    for (int i = 0; i < 8; ++i)
      o8[i] = f2bf((v[i]-mu)*rstd*gg[i] + bb[i]);
    *(uint4*)(x1b + row*512 + d0) = *(const uint4*)o8;
    return;
  }
  // ---- transpose path ----
  const float* W; u16* WT; int R, C;
  switch (z){
    case 0:  W = W0; WT = T0; R = 512;  C = 1024; break;
    case 1:  W = W1; WT = T1; R = 512;  C = 1024; break;
    case 2:  W = W2; WT = T2; R = 512;  C = 1024; break;
    case 3:  W = W3; WT = T3; R = 1024; C = 512;  break;
    case 4:  W = W4; WT = T4; R = 512;  C = 1024; break;
    default: W = W5; WT = T5; R = 1024; C = 512;  break;
  }
  const int c0 = blockIdx.x * 32, r0 = blockIdx.y * 32;
  if (c0 >= C || r0 >= R) return;
  __shared__ float tile[32][33];
  const int tx = threadIdx.x, ty = threadIdx.y;  // (32,8)
  #pragma unroll
  for (int j = 0; j < 4; ++j)
    tile[ty + j*8][tx] = W[(size_t)(r0 + ty + j*8) * C + (c0 + tx)];
  __syncthreads();
  #pragma unroll
  for (int j = 0; j < 4; ++j)
    WT[(size_t)(c0 + ty + j*8) * R + (r0 + tx)] = f2bf(tile[tx][ty + j*8]);
}

// ---------------- LayerNorm (standalone, used for LN2) ----------------
template<bool BF16IN>
__global__ __launch_bounds__(256)
void ln_kernel(const void* __restrict__ xin, const float* __restrict__ gamma,
               const float* __restrict__ beta, u16* __restrict__ xout){
  const int wid = threadIdx.x >> 6;
  const int lane = threadIdx.x & 63;
  const size_t row = (size_t)blockIdx.x * 4 + wid;
  const int d0 = lane * 8;
  float v[8];
  if constexpr (BF16IN){
    const u16* xp = (const u16*)xin + row * 512 + d0;
    uint4 p = *(const uint4*)xp;
    const u16* s = (const u16*)&p;
    #pragma unroll
    for (int i = 0; i < 8; ++i) v[i] = bf2f(s[i]);
  } else {
    const float* xp = (const float*)xin + row * 512 + d0;
    float4 p0 = *(const float4*)xp;
    float4 p1 = *(const float4*)(xp + 4);
    v[0]=p0.x; v[1]=p0.y; v[2]=p0.z; v[3]=p0.w;
    v[4]=p1.x; v[5]=p1.y; v[6]=p1.z; v[7]=p1.w;
  }
  float s = 0.f, sq = 0.f;
  #pragma unroll
  for (int i = 0; i < 8; ++i){ s += v[i]; sq += v[i]*v[i]; }
  #pragma unroll
  for (int o = 32; o >= 1; o >>= 1){ s += __shfl_xor(s, o); sq += __shfl_xor(sq, o); }
  const float mu  = s * (1.0f/512.0f);
  const float var = sq * (1.0f/512.0f) - mu*mu;
  const float rstd = rsqrtf(var + 1e-5f);
  const float4 g0 = *(const float4*)(gamma + d0);
  const float4 g1 = *(const float4*)(gamma + d0 + 4);
  const float4 b0 = *(const float4*)(beta + d0);
  const float4 b1 = *(const float4*)(beta + d0 + 4);
  float gg[8] = {g0.x,g0.y,g0.z,g0.w,g1.x,g1.y,g1.z,g1.w};
  float bb[8] = {b0.x,b0.y,b0.z,b0.w,b1.x,b1.y,b1.z,b1.w};
  u16 o8[8];
  #pragma unroll
  for (int i = 0; i < 8; ++i)
    o8[i] = f2bf((v[i]-mu)*rstd*gg[i] + bb[i]);
  *(uint4*)(xout + row*512 + d0) = *(const uint4*)o8;
}

// ---- fused AFT: weighted[t,h] = sum_b n*v / sum_b n ; Yt[b,t,h] = Qsig[b,t,h]*weighted ----
__global__ __launch_bounds__(256)
void aft_fused(const u16* __restrict__ numer, const u16* __restrict__ V,
               const u16* __restrict__ qs, u16* __restrict__ yt){
  const size_t TH = (size_t)4096 * 1024;
  const size_t i8 = ((size_t)blockIdx.x * 256 + threadIdx.x) * 8;
  float den[8], ws[8];
  #pragma unroll
  for (int j = 0; j < 8; ++j){ den[j] = 0.f; ws[j] = 0.f; }
  #pragma unroll
  for (int b = 0; b < 8; ++b){
    uint4 pn = *(const uint4*)(numer + b*TH + i8);
    uint4 pv = *(const uint4*)(V     + b*TH + i8);
    const u16* n = (const u16*)&pn;
    const u16* v = (const u16*)&pv;
    #pragma unroll
    for (int j = 0; j < 8; ++j){ float nf = bf2f(n[j]); den[j] += nf; ws[j] += nf * bf2f(v[j]); }
  }
  float w[8];
  #pragma unroll
  for (int j = 0; j < 8; ++j) w[j] = ws[j] * fast_rcp(den[j]);
  #pragma unroll
  for (int b = 0; b < 8; ++b){
    uint4 pq = *(const uint4*)(qs + b*TH + i8);
    const u16* q = (const u16*)&pq;
    u16 o[8];
    #pragma unroll
    for (int j = 0; j < 8; ++j) o[j] = f2bf(bf2f(q[j]) * w[j]);
    *(uint4*)(yt + b*TH + i8) = *(const uint4*)o;
  }
}

// ---------------- 128x128 bf16 MFMA GEMM (R0-verified; used for QKV / EPI 0) ----------------
// 68 VGPR + 64 AGPR -> 3 blocks/CU (12 waves/CU): inter-block overlap hides the 2-phase
// barrier drain. Best measured QKV config of the session (147.2 us, 700 TF).
template<int EPI, int KC>
__global__ __launch_bounds__(256, 3)
void gemm128(const u16* __restrict__ A, const u16* __restrict__ Bt, int nTiles,
             const float* __restrict__ bias0, const float* __restrict__ wbias,
             u16* __restrict__ out0, u16* __restrict__ out1, u16* __restrict__ out2,
             const float* __restrict__ bias1, const float* __restrict__ bias2,
             const u16* __restrict__ resid, float* __restrict__ outf){
  __shared__ u16 ldsA[128*64];
  __shared__ u16 ldsB[128*64];
  const int tid  = threadIdx.x;
  const int wid  = tid >> 6;
  const int lane = tid & 63;
  const int quad = lane >> 4;
  const int lr   = lane & 15;

  // swizzled tile decode: groups of 16 M-tiles x all N-tiles, M fastest -> XCD pinning
  const int lin = blockIdx.x;
  const int GS  = 16 * nTiles;
  const int g   = lin / GS;
  const int rem = lin - g * GS;
  const int tileM = (g * 16 + (rem & 15)) * 128;
  const int tileN = (rem >> 4) * 128;

  const int wmBase = (wid & 1) * 64;
  const int wnBase = (wid >> 1) * 64;

  f32x4 acc[4][4] = {};

  // Staging source mapping; XOR swizzle on GLOBAL source, LDS write linear.
  int srow[4], scb[4];
  #pragma unroll
  for (int r = 0; r < 4; ++r){
    const int off = r*4096 + wid*1024 + lane*16;  // byte offset in 16KB tile
    srow[r] = off >> 7;                           // 128B per 64-col bf16 row
    scb[r]  = ((off >> 4) & 7) ^ (srow[r] & 7);
  }
  const u16* aSrc[4]; const u16* bSrc[4];
  #pragma unroll
  for (int r = 0; r < 4; ++r){
    aSrc[r] = A  + (size_t)(tileM + srow[r]) * KC + scb[r]*8;
    bSrc[r] = Bt + (size_t)(tileN + srow[r]) * KC + scb[r]*8;
  }

  // hoisted LDS fragment byte-offsets (loop-invariant)
  int aOff[2][4], bOff[2][4];
  #pragma unroll
  for (int s = 0; s < 2; ++s)
    #pragma unroll
    for (int i = 0; i < 4; ++i){
      const int m = wmBase + i*16 + lr;
      const int n = wnBase + i*16 + lr;
      aOff[s][i] = m*128 + (((s*4 + quad) ^ (m & 7)) * 16);
      bOff[s][i] = n*128 + (((s*4 + quad) ^ (n & 7)) * 16);
    }

  #pragma unroll
  for (int kt = 0; kt < KC; kt += 64){
    #pragma unroll
    for (int r = 0; r < 4; ++r){
      async16(aSrc[r] + kt, (u16*)((char*)ldsA + r*4096 + wid*1024));
      async16(bSrc[r] + kt, (u16*)((char*)ldsB + r*4096 + wid*1024));
    }
    __syncthreads();
    #pragma unroll
    for (int s = 0; s < 2; ++s){
      bf16x8 ar[4], br[4];
      #pragma unroll
      for (int i = 0; i < 4; ++i) ar[i] = *(const bf16x8*)((const char*)ldsA + aOff[s][i]);
      #pragma unroll
      for (int i = 0; i < 4; ++i) br[i] = *(const bf16x8*)((const char*)ldsB + bOff[s][i]);
      #pragma unroll
      for (int i = 0; i < 4; ++i)
        #pragma unroll
        for (int j = 0; j < 4; ++j)
          acc[i][j] = __builtin_amdgcn_mfma_f32_16x16x32_bf16(br[j], ar[i], acc[i][j], 0, 0, 0);
    }
    __syncthreads();
  }

  // ---- epilogue ----
  if (EPI == 3){
    #pragma unroll
    for (int j = 0; j < 4; ++j){
      const int colb = tileN + wnBase + j*16 + quad*4;
      const float4 bvv = *(const float4*)(bias0 + colb);
      #pragma unroll
      for (int i = 0; i < 4; ++i){
        const int row = tileM + wmBase + i*16 + lr;
        float4 o;
        #pragma unroll
        for (int r = 0; r < 4; ++r)
          ((float*)&o)[r] = 2.0f * (acc[i][j][r] + ((const float*)&bvv)[r]);
        *(float4*)(outf + (size_t)row * 512 + colb) = o;
      }
    }
    return;
  }

  // bf16 epilogues with LDS bounce.
  u16* eb = ldsA + wid * 1152;          // u16 units; row stride 72 u16 (144 B)
  const int mat = (EPI == 0) ? (tileN >> 10) : 0;   // 0:Q 1:K 2:V
  const float* biasP = bias0;
  u16* outP = out0;
  int ldO = 1024, cb0 = tileN + wnBase;
  if (EPI == 0){
    biasP = (mat==0) ? bias0 : (mat==1) ? bias1 : bias2;
    outP  = (mat==0) ? out0  : (mat==1) ? out1  : out2;
    cb0   = (tileN & 1023) + wnBase;
  } else if (EPI == 1){
    ldO = 512;
  }

  #pragma unroll
  for (int i = 0; i < 4; ++i){
    const int row = tileM + wmBase + i*16 + lr;
    #pragma unroll
    for (int j = 0; j < 4; ++j){
      const int cl = j*16 + quad*4;
      const float4 bvv = *(const float4*)(biasP + cb0 + cl);
      u16 o[4];
      if (EPI == 0){
        float4 wbv = {0,0,0,0};
        if (mat == 1) wbv = *(const float4*)(wbias + cb0 + cl);
        #pragma unroll
        for (int r = 0; r < 4; ++r){
          float v = acc[i][j][r] + ((const float*)&bvv)[r];
          if (mat == 0)      v = fast_rcp(1.0f + __expf(-v));
          else if (mat == 1) v = __expf(v + ((const float*)&wbv)[r]);
          o[r] = f2bf(v);
        }
      } else if (EPI == 1){
        uint2 pr = *(const uint2*)(resid + (size_t)row * 512 + cb0 + cl);
        const u16* rp = (const u16*)&pr;
        #pragma unroll
        for (int r = 0; r < 4; ++r)
          o[r] = f2bf(acc[i][j][r] + ((const float*)&bvv)[r] + bf2f(rp[r]));
      } else {
        #pragma unroll
        for (int r = 0; r < 4; ++r){
          float v = acc[i][j][r] + ((const float*)&bvv)[r];
          float u2 = 2.0f * v * (0.7978845608f + 0.0356774081f * v * v);
          float t  = 1.0f - 2.0f * fast_rcp(1.0f + __expf(u2));
          o[r] = f2bf(0.5f * v * (1.0f + t));
        }
      }
      *(uint2*)(eb + lr*72 + cl) = *(const uint2*)o;
    }
    __asm__ volatile("s_waitcnt lgkmcnt(0)" ::: "memory");
    uint4 p0 = *(const uint4*)(eb + lr*72 + quad*16);
    uint4 p1 = *(const uint4*)(eb + lr*72 + quad*16 + 8);
    __asm__ volatile("s_waitcnt lgkmcnt(0)" ::: "memory");
    u16* gp = outP + (size_t)row * ldO + cb0 + quad*16;
    *(uint4*)gp = p0;
    *(uint4*)(gp + 8) = p1;
  }
}

// ======== 256x256 bf16 MFMA GEMM (R3-verified; used for EPI 1,2,3) ========
template<int EPI, int KC>
__global__ __launch_bounds__(512, 2)
void gemm256(const u16* __restrict__ A, const u16* __restrict__ Bt,
             const float* __restrict__ bias0, const float* __restrict__ wbias,
             u16* __restrict__ out0, u16* __restrict__ out1, u16* __restrict__ out2,
             const float* __restrict__ bias1, const float* __restrict__ bias2,
             const u16* __restrict__ resid, float* __restrict__ outf){
  constexpr int NK = KC / 64;
  __shared__ __align__(16) char smem[65536];  // A0|A1|B0|B1, 16 KiB each

  const int tid  = threadIdx.x;
  const int wid  = tid >> 6;
  const int lane = tid & 63;
  const int quad = lane >> 4;
  const int lr   = lane & 15;
  const int wm   = wid & 1;      // M-wave (2)
  const int wn   = wid >> 1;     // N-wave (4)

  // bijective XCD swizzle + L2 supergroups (4 M-tiles x all N-tiles, M fastest)
  const int nwg = gridDim.x;                 // = 128 * nNT (always % 8 == 0)
  const int wg  = (blockIdx.x & 7) * (nwg >> 3) + (blockIdx.x >> 3);
  const int nNT = nwg >> 7;                  // N-tiles: 2 / 4 / 2
  const int sgs = nNT << 2;                  // supergroup size (4*nNT)
  const int sg  = wg / sgs;
  const int r   = wg - sg * sgs;
  const int tileM = (sg*4 + (r & 3)) * 256;
  const int tileN = (r >> 2) * 256;

  // ---- staging source pointers (pre-swizzled global addresses) ----
  const u16* sA[2][2]; const u16* sB[2][2];
  {
    const int off0 = wid*1024 + lane*16;
    #pragma unroll
    for (int rr_ = 0; rr_ < 2; ++rr_){
      const int off = rr_*8192 + off0;        // byte pos inside 16KB half
      const int rr  = off >> 7;               // 0..127
      const int g   = (((off >> 4) & 7) ^ (rr & 7)) * 8;   // swizzled k-chunk (elems)
      #pragma unroll
      for (int h = 0; h < 2; ++h){
        sA[h][rr_] = A  + (size_t)(tileM + (rr>>6)*128 + h*64 + (rr&63)) * KC + g;
        sB[h][rr_] = Bt + (size_t)(tileN + (rr>>5)*64  + h*32 + (rr&31)) * KC + g;
      }
    }
  }
  auto stA = [&](int h, int kt){
    char* d = smem + h*16384 + wid*1024;
    async16(sA[h][0] + kt, (u16*)d);
    async16(sA[h][1] + kt, (u16*)(d + 8192));
  };
  auto stB = [&](int h, int kt){
    char* d = smem + 32768 + h*16384 + wid*1024;
    async16(sB[h][0] + kt, (u16*)d);
    async16(sB[h][1] + kt, (u16*)(d + 8192));
  };

  // ---- fragment read offsets ----
  const int cO0  = ((quad)     ^ (lr & 7)) * 16;   // ks=0 swizzled chunk byte
  const int cO1  = ((quad ^ 4) ^ (lr & 7)) * 16;   // ks=1
  const int aRow = (wm*64 + lr) * 128;             // + mh*16384 + i*2048
  const int bRow = (wn*32 + lr) * 128;             // + 32768 + nh*16384 + j*2048

  bf16x8 ar[4][2], br0[2][2], br1[2][2];
  f32x4 acc[2][2][4][2] = {};   // [mh][nh][i][j]

  auto ldA = [&](int mh){
    #pragma unroll
    for (int i = 0; i < 4; ++i){
      ar[i][0] = *(const bf16x8*)(smem + mh*16384 + aRow + i*2048 + cO0);
      ar[i][1] = *(const bf16x8*)(smem + mh*16384 + aRow + i*2048 + cO1);
    }
  };
  auto ldB = [&](int nh, bf16x8 (&br)[2][2]){
    #pragma unroll
    for (int j = 0; j < 2; ++j){
      br[j][0] = *(const bf16x8*)(smem + 32768 + nh*16384 + bRow + j*2048 + cO0);
      br[j][1] = *(const bf16x8*)(smem + 32768 + nh*16384 + bRow + j*2048 + cO1);
    }
  };
  auto MF = [&](int mh, int nh, bf16x8 (&br)[2][2]){
    __builtin_amdgcn_s_setprio(1);
    #pragma unroll
    for (int i = 0; i < 4; ++i)
      #pragma unroll
      for (int j = 0; j < 2; ++j){
        acc[mh][nh][i][j] = __builtin_amdgcn_mfma_f32_16x16x32_bf16(br[j][0], ar[i][0], acc[mh][nh][i][j], 0, 0, 0);
        acc[mh][nh][i][j] = __builtin_amdgcn_mfma_f32_16x16x32_bf16(br[j][1], ar[i][1], acc[mh][nh][i][j], 0, 0, 0);
      }
    __builtin_amdgcn_s_setprio(0);
  };

  // ---- prologue: stage tile0 (A0,B0 oldest -> vmcnt(4) waits exactly those) ----
  stA(0, 0); stB(0, 0); stB(1, 0); stA(1, 0);
  VMCNT(4);
  BARRIER();

  // ---- main loop (tiles 0..NK-2), tail peeled ----
  #pragma unroll 1
  for (int t = 0; t < NK-1; ++t){
    const int kt = (t+1)*64;
    // q0
    ldA(0); ldB(0, br0);
    BARRIER(); LGKM0();
    MF(0, 0, br0);
    VMCNT(2);                       // B1(t) landed (staged q2(t-1))
    BARRIER();
    // q1
    ldB(1, br1);
    stA(0, kt); stB(0, kt);         // slots A0,B0 freed after q0
    BARRIER(); LGKM0();
    MF(0, 1, br1);
    VMCNT(4);                       // A1(t) landed (staged q3(t-1))
    BARRIER();
    // q2
    ldA(1);
    stB(1, kt);                     // slot B1 freed after q1
    BARRIER(); LGKM0();
    MF(1, 1, br1);
    BARRIER();
    // q3 (no LDS read: A1 in ar, B0 held in br0)
    stA(1, kt);                     // slot A1 freed after q2
    MF(1, 0, br0);
    VMCNT(4);                       // A0,B0(t+1) landed (staged q1(t))
    BARRIER();
  }
  // ---- tail tile (no staging; drain) ----
  ldA(0); ldB(0, br0);
  BARRIER(); LGKM0();
  MF(0, 0, br0);
  VMCNT(2);
  BARRIER();
  ldB(1, br1);
  BARRIER(); LGKM0();
  MF(0, 1, br1);
  VMCNT(0);                         // A1 of last tile (only 2 loads left)
  BARRIER();
  ldA(1);
  BARRIER(); LGKM0();
  MF(1, 1, br1);
  BARRIER();                        // all LDS reads done -> smem reusable below
  MF(1, 0, br0);

  // ---- epilogue ----
  if (EPI == 3){
    #pragma unroll
    for (int mh = 0; mh < 2; ++mh)
    #pragma unroll
    for (int i = 0; i < 4; ++i){
      const int row = tileM + wm*128 + mh*64 + i*16 + lr;
      #pragma unroll
      for (int nh = 0; nh < 2; ++nh)
      #pragma unroll
      for (int j = 0; j < 2; ++j){
        const int colb = tileN + wn*64 + nh*32 + j*16 + quad*4;
        const float4 bvv = *(const float4*)(bias0 + colb);
        float4 o;
        #pragma unroll
        for (int r_ = 0; r_ < 4; ++r_)
          ((float*)&o)[r_] = 2.0f * (acc[mh][nh][i][j][r_] + ((const float*)&bvv)[r_]);
        *(float4*)(outf + (size_t)row * 512 + colb) = o;
      }
    }
    return;
  }

  // bf16 epilogues with per-wave LDS bounce -> full 128-B-line global stores.
  char* eb = smem + wid * 2304;              // 16 rows x 144 B
  const int mat = 0;
  const float* biasP = bias0;
  u16* outP = out0;
  int ldO = 1024, cb0 = tileN + wn*64;
  if (EPI == 1){
    ldO = 512;
  }
  (void)mat;

  #pragma unroll
  for (int mh = 0; mh < 2; ++mh)
  #pragma unroll
  for (int i = 0; i < 4; ++i){
    const int row = tileM + wm*128 + mh*64 + i*16 + lr;
    #pragma unroll
    for (int nh = 0; nh < 2; ++nh)
    #pragma unroll
    for (int j = 0; j < 2; ++j){
      const int cl = (nh*2 + j)*16 + quad*4;
      const float4 bvv = *(const float4*)(biasP + cb0 + cl);
      u16 o[4];
      if (EPI == 1){
        uint2 pr = *(const uint2*)(resid + (size_t)row * 512 + cb0 + cl);
        const u16* rp = (const u16*)&pr;
        #pragma unroll
        for (int r_ = 0; r_ < 4; ++r_)
          o[r_] = f2bf(acc[mh][nh][i][j][r_] + ((const float*)&bvv)[r_] + bf2f(rp[r_]));
      } else {
        #pragma unroll
        for (int r_ = 0; r_ < 4; ++r_){
          float v  = acc[mh][nh][i][j][r_] + ((const float*)&bvv)[r_];
          float u2 = 2.0f * v * (0.7978845608f + 0.0356774081f * v * v);
          float tg = 1.0f - 2.0f * fast_rcp(1.0f + __expf(u2));
          o[r_] = f2bf(0.5f * v * (1.0f + tg));
        }
      }
      *(uint2*)(eb + lr*144 + cl*2) = *(const uint2*)o;
    }
    __asm__ volatile("s_waitcnt lgkmcnt(0)" ::: "memory");
    uint4 p0 = *(const uint4*)(eb + lr*144 + quad*32);
    uint4 p1 = *(const uint4*)(eb + lr*144 + quad*32 + 16);
    __asm__ volatile("s_waitcnt lgkmcnt(0)" ::: "memory");
    u16* gp = outP + (size_t)row * ldO + cb0 + quad*16;
    *(uint4*)gp = p0;
    *(uint4*)(gp + 8) = p1;
  }
}

extern "C" void kernel_launch(void* const* d_in, const int* in_sizes, int n_in,
                              void* d_out, int out_size, void* d_ws, size_t ws_size,
                              hipStream_t stream) {
  const float* x     = (const float*)d_in[0];
  const float* gamma = (const float*)d_in[1];
  const float* beta  = (const float*)d_in[2];
  const float* Wq    = (const float*)d_in[3];
  const float* bq    = (const float*)d_in[4];
  const float* Wk    = (const float*)d_in[5];
  const float* bk    = (const float*)d_in[6];
  const float* Wv    = (const float*)d_in[7];
  const float* bv    = (const float*)d_in[8];
  const float* wbias = (const float*)d_in[9];
  const float* Wo    = (const float*)d_in[10];
  const float* bo    = (const float*)d_in[11];
  const float* W1    = (const float*)d_in[12];
  const float* b1    = (const float*)d_in[13];
  const float* W2    = (const float*)d_in[14];
  const float* b2    = (const float*)d_in[15];
  float* out = (float*)d_out;

  char* w = (char*)d_ws;
  const size_t MB = 1ull << 20;
  u16* WqkvT = (u16*)(w + 0*MB);      // [3072][512]  (WqT | WkT | WvT)
  u16* WoT   = (u16*)(w + 3*MB);      // [512][1024]
  u16* W1T   = (u16*)(w + 4*MB);      // [1024][512]
  u16* W2T   = (u16*)(w + 5*MB);      // [512][1024]
  u16* x1b   = (u16*)(w + 6*MB);      // [32768][512]
  u16* Qs    = (u16*)(w + 38*MB);     // [32768][1024]
  u16* Nu    = (u16*)(w + 102*MB);    // [32768][1024]
  u16* Vb    = (u16*)(w + 166*MB);    // [32768][1024]
  u16* Yt    = Nu;                    // in-place over numer
  u16* x2b   = Vb;                    // reuse (V consumed by aft_fused)
  u16* x3b   = (u16*)(w + 198*MB);
  u16* hb    = Qs;                    // reuse (Qsig consumed by aft_fused)

  // fused: 6 weight transposes (z=0..5) + LN1 (z=6..13), one dispatch
  prep_fused<<<dim3(32, 32, 14), dim3(32, 8), 0, stream>>>(
      Wq, Wk, Wv, Wo, W1, W2,
      WqkvT, WqkvT + 1024*512, WqkvT + 2*1024*512, WoT, W1T, W2T,
      x, gamma, beta, x1b);

  // QKV: [32768,512] @ [3072,512]^T ; 256 M-tiles x 24 N-tiles (128^2, 3 blocks/CU)
  gemm128<0, 512><<<256*24, 256, 0, stream>>>(x1b, WqkvT, 24,
      bq, wbias, Qs, Nu, Vb, bk, bv, nullptr, nullptr);

  aft_fused<<<2048, 256, 0, stream>>>(Nu, Vb, Qs, Yt);

  // attn out: [32768,1024] @ [512,1024]^T ; 128 x 2 (256^2)
  gemm256<1, 1024><<<256, 512, 0, stream>>>(Yt, WoT,
      bo, nullptr, x2b, nullptr, nullptr, nullptr, nullptr, x1b, nullptr);

  ln_kernel<true><<<8192, 256, 0, stream>>>(x2b, gamma, beta, x3b);

  // mlp1: [32768,512] @ [1024,512]^T ; 128 x 4 (256^2)
  gemm256<2, 512><<<512, 512, 0, stream>>>(x3b, W1T,
      b1, nullptr, hb, nullptr, nullptr, nullptr, nullptr, nullptr, nullptr);

  // mlp2: [32768,1024] @ [512,1024]^T ; 128 x 2 (256^2)
  gemm256<3, 1024><<<256, 512, 0, stream>>>(hb, W2T,
      b2, nullptr, nullptr, nullptr, nullptr, nullptr, nullptr, nullptr, out);
}

// Round 9
// 475.429 us; speedup vs baseline: 1.2052x; 1.0108x over previous
//
#include <hip/hip_runtime.h>
#include <hip/hip_bf16.h>
#include <cstdint>

using u16 = unsigned short;
using u32 = unsigned int;

typedef __bf16 bf16x8 __attribute__((ext_vector_type(8)));
typedef float  f32x4  __attribute__((ext_vector_type(4)));

#define DEV static __device__ __forceinline__

DEV float bf2f(u16 u){ union { u32 u; float f; } c; c.u = ((u32)u) << 16; return c.f; }

// hardware RNE f32->bf16
DEV u16 f2bf(float f){
  __bf16 h = (__bf16)f;
  return __builtin_bit_cast(u16, h);
}

DEV float fast_rcp(float x){ return __builtin_amdgcn_rcpf(x); }

DEV void async16(const u16* g, u16* l){
  __builtin_amdgcn_global_load_lds((const __attribute__((address_space(1))) u32*)g,
                                   (__attribute__((address_space(3))) u32*)l,
                                   16, 0, 0);
}

#define BARRIER() __builtin_amdgcn_s_barrier()
#define LGKM0() do { __asm__ volatile("s_waitcnt lgkmcnt(0)" ::: "memory"); \
                     __builtin_amdgcn_sched_barrier(0); } while (0)
#define VMCNT(n) __asm__ volatile("s_waitcnt vmcnt(" #n ")" ::: "memory")

// ======== fused prep: 6 weight transposes (f32->bf16) + LayerNorm1, one dispatch ========
__global__ __launch_bounds__(256)
void prep_fused(const float* __restrict__ W0, const float* __restrict__ W1,
                const float* __restrict__ W2, const float* __restrict__ W3,
                const float* __restrict__ W4, const float* __restrict__ W5,
                u16* __restrict__ T0, u16* __restrict__ T1, u16* __restrict__ T2,
                u16* __restrict__ T3, u16* __restrict__ T4, u16* __restrict__ T5,
                const float* __restrict__ x, const float* __restrict__ gamma,
                const float* __restrict__ beta, u16* __restrict__ x1b){
  const int z = blockIdx.z;
  if (z >= 6){
    // ---- LayerNorm path: one wave per 512-elem row ----
    const int bid = (z - 6) * 1024 + blockIdx.y * 32 + blockIdx.x;
    const int tid = threadIdx.y * 32 + threadIdx.x;
    const int wid = tid >> 6;
    const int lane = tid & 63;
    const size_t row = (size_t)bid * 4 + wid;
    const int d0 = lane * 8;
    const float* xp = x + row * 512 + d0;
    float4 p0 = *(const float4*)xp;
    float4 p1 = *(const float4*)(xp + 4);
    float v[8] = {p0.x,p0.y,p0.z,p0.w,p1.x,p1.y,p1.z,p1.w};
    float s = 0.f, sq = 0.f;
    #pragma unroll
    for (int i = 0; i < 8; ++i){ s += v[i]; sq += v[i]*v[i]; }
    #pragma unroll
    for (int o = 32; o >= 1; o >>= 1){ s += __shfl_xor(s, o); sq += __shfl_xor(sq, o); }
    const float mu  = s * (1.0f/512.0f);
    const float var = sq * (1.0f/512.0f) - mu*mu;
    const float rstd = rsqrtf(var + 1e-5f);
    const float4 g0 = *(const float4*)(gamma + d0);
    const float4 g1 = *(const float4*)(gamma + d0 + 4);
    const float4 b0 = *(const float4*)(beta + d0);
    const float4 b1 = *(const float4*)(beta + d0 + 4);
    float gg[8] = {g0.x,g0.y,g0.z,g0.w,g1.x,g1.y,g1.z,g1.w};
    float bb[8] = {b0.x,b0.y,b0.z,b0.w,b1.x,b1.y,b1.z,b1.w};
    u16 o8[8];
    #pragma unroll
    for (int i = 0; i < 8; ++i)
      o8[i] = f2bf((v[i]-mu)*rstd*gg[i] + bb[i]);
    *(uint4*)(x1b + row*512 + d0) = *(const uint4*)o8;
    return;
  }
  // ---- transpose path ----
  const float* W; u16* WT; int R, C;
  switch (z){
    case 0:  W = W0; WT = T0; R = 512;  C = 1024; break;
    case 1:  W = W1; WT = T1; R = 512;  C = 1024; break;
    case 2:  W = W2; WT = T2; R = 512;  C = 1024; break;
    case 3:  W = W3; WT = T3; R = 1024; C = 512;  break;
    case 4:  W = W4; WT = T4; R = 512;  C = 1024; break;
    default: W = W5; WT = T5; R = 1024; C = 512;  break;
  }
  const int c0 = blockIdx.x * 32, r0 = blockIdx.y * 32;
  if (c0 >= C || r0 >= R) return;
  __shared__ float tile[32][33];
  const int tx = threadIdx.x, ty = threadIdx.y;  // (32,8)
  #pragma unroll
  for (int j = 0; j < 4; ++j)
    tile[ty + j*8][tx] = W[(size_t)(r0 + ty + j*8) * C + (c0 + tx)];
  __syncthreads();
  #pragma unroll
  for (int j = 0; j < 4; ++j)
    WT[(size_t)(c0 + ty + j*8) * R + (r0 + tx)] = f2bf(tile[tx][ty + j*8]);
}

// ---------------- LayerNorm (standalone, used for LN2) ----------------
template<bool BF16IN>
__global__ __launch_bounds__(256)
void ln_kernel(const void* __restrict__ xin, const float* __restrict__ gamma,
               const float* __restrict__ beta, u16* __restrict__ xout){
  const int wid = threadIdx.x >> 6;
  const int lane = threadIdx.x & 63;
  const size_t row = (size_t)blockIdx.x * 4 + wid;
  const int d0 = lane * 8;
  float v[8];
  if constexpr (BF16IN){
    const u16* xp = (const u16*)xin + row * 512 + d0;
    uint4 p = *(const uint4*)xp;
    const u16* s = (const u16*)&p;
    #pragma unroll
    for (int i = 0; i < 8; ++i) v[i] = bf2f(s[i]);
  } else {
    const float* xp = (const float*)xin + row * 512 + d0;
    float4 p0 = *(const float4*)xp;
    float4 p1 = *(const float4*)(xp + 4);
    v[0]=p0.x; v[1]=p0.y; v[2]=p0.z; v[3]=p0.w;
    v[4]=p1.x; v[5]=p1.y; v[6]=p1.z; v[7]=p1.w;
  }
  float s = 0.f, sq = 0.f;
  #pragma unroll
  for (int i = 0; i < 8; ++i){ s += v[i]; sq += v[i]*v[i]; }
  #pragma unroll
  for (int o = 32; o >= 1; o >>= 1){ s += __shfl_xor(s, o); sq += __shfl_xor(sq, o); }
  const float mu  = s * (1.0f/512.0f);
  const float var = sq * (1.0f/512.0f) - mu*mu;
  const float rstd = rsqrtf(var + 1e-5f);
  const float4 g0 = *(const float4*)(gamma + d0);
  const float4 g1 = *(const float4*)(gamma + d0 + 4);
  const float4 b0 = *(const float4*)(beta + d0);
  const float4 b1 = *(const float4*)(beta + d0 + 4);
  float gg[8] = {g0.x,g0.y,g0.z,g0.w,g1.x,g1.y,g1.z,g1.w};
  float bb[8] = {b0.x,b0.y,b0.z,b0.w,b1.x,b1.y,b1.z,b1.w};
  u16 o8[8];
  #pragma unroll
  for (int i = 0; i < 8; ++i)
    o8[i] = f2bf((v[i]-mu)*rstd*gg[i] + bb[i]);
  *(uint4*)(xout + row*512 + d0) = *(const uint4*)o8;
}

// ---- AFT reduction only: weighted[t,h] = sum_b numer*V / sum_b numer  (Wt in-place over Nu) ----
// Each thread owns 8 (t,h) columns: reads numer/V across b, writes Wt at its own i8 —
// single-owner-per-column, same in-place pattern as the verified Yt-over-Nu write.
__global__ __launch_bounds__(256)
void aft_weighted(const u16* __restrict__ numer, const u16* __restrict__ V,
                  u16* __restrict__ wt){
  const size_t TH = (size_t)4096 * 1024;
  const size_t i8 = ((size_t)blockIdx.x * 256 + threadIdx.x) * 8;
  float den[8], ws[8];
  #pragma unroll
  for (int j = 0; j < 8; ++j){ den[j] = 0.f; ws[j] = 0.f; }
  #pragma unroll
  for (int b = 0; b < 8; ++b){
    uint4 pn = *(const uint4*)(numer + b*TH + i8);
    uint4 pv = *(const uint4*)(V     + b*TH + i8);
    const u16* n = (const u16*)&pn;
    const u16* v = (const u16*)&pv;
    #pragma unroll
    for (int j = 0; j < 8; ++j){ float nf = bf2f(n[j]); den[j] += nf; ws[j] += nf * bf2f(v[j]); }
  }
  u16 o[8];
  #pragma unroll
  for (int j = 0; j < 8; ++j) o[j] = f2bf(ws[j] * fast_rcp(den[j]));
  *(uint4*)(wt + i8) = *(const uint4*)o;
}

// ======== 128x128 GEMM with FUSED A = Qsig ⊙ weighted (attn-out, EPI1 semantics) ========
// x2 = (Qs .* Wt[t]) @ WoT^T + bo + resid.  2-phase lockstep, 3 blocks/CU (R0-proven).
// A staged via reg: 8 linear dwordx4 loads (Qs,Wt) -> bf16 multiply -> swizzled ds_write
// (slot cb^(row&7); read side unchanged -> both-sides-consistent). B via global_load_lds.
// Compiler-inserted waitcnts order loads->multiply; __syncthreads drains B + ds_writes.
__global__ __launch_bounds__(256, 3)
void gemm128_yt(const u16* __restrict__ Qs, const u16* __restrict__ Bt, int nTiles,
                const u16* __restrict__ Wt, const float* __restrict__ bias0,
                u16* __restrict__ out0, const u16* __restrict__ resid){
  constexpr int KC = 1024;
  __shared__ u16 ldsA[128*64];
  __shared__ u16 ldsB[128*64];
  const int tid  = threadIdx.x;
  const int wid  = tid >> 6;
  const int lane = tid & 63;
  const int quad = lane >> 4;
  const int lr   = lane & 15;

  const int lin = blockIdx.x;
  const int GS  = 16 * nTiles;
  const int g   = lin / GS;
  const int rem = lin - g * GS;
  const int tileM = (g * 16 + (rem & 15)) * 128;
  const int tileN = (rem >> 4) * 128;

  const int wmBase = (wid & 1) * 64;
  const int wnBase = (wid >> 1) * 64;

  f32x4 acc[4][4] = {};

  // staging maps
  int srow[4], cb[4], dOff[4], scb[4];
  #pragma unroll
  for (int r = 0; r < 4; ++r){
    const int off = r*4096 + wid*1024 + lane*16;  // byte offset in 16KB tile
    srow[r] = off >> 7;
    cb[r]   = (off >> 4) & 7;                     // linear chunk (A path)
    dOff[r] = srow[r]*128 + ((cb[r] ^ (srow[r] & 7)) << 4);  // swizzled LDS dest
    scb[r]  = cb[r] ^ (srow[r] & 7);              // pre-swizzled chunk (B path)
  }
  const u16* aSrc[4]; const u16* wSrc[4]; const u16* bSrc[4];
  #pragma unroll
  for (int r = 0; r < 4; ++r){
    aSrc[r] = Qs + (size_t)(tileM + srow[r]) * KC + cb[r]*8;          // linear
    wSrc[r] = Wt + (size_t)((tileM + srow[r]) & 4095) * 1024 + cb[r]*8;
    bSrc[r] = Bt + (size_t)(tileN + srow[r]) * KC + scb[r]*8;         // pre-swizzled
  }

  // fragment read offsets (unchanged from verified gemm128)
  int aOff[2][4], bOff[2][4];
  #pragma unroll
  for (int s = 0; s < 2; ++s)
    #pragma unroll
    for (int i = 0; i < 4; ++i){
      const int m = wmBase + i*16 + lr;
      const int n = wnBase + i*16 + lr;
      aOff[s][i] = m*128 + (((s*4 + quad) ^ (m & 7)) * 16);
      bOff[s][i] = n*128 + (((s*4 + quad) ^ (n & 7)) * 16);
    }

  #pragma unroll 1
  for (int kt = 0; kt < KC; kt += 64){
    // A: reg-stage fused multiply
    uint4 qa[4], wa[4];
    #pragma unroll
    for (int r = 0; r < 4; ++r) qa[r] = *(const uint4*)(aSrc[r] + kt);
    #pragma unroll
    for (int r = 0; r < 4; ++r) wa[r] = *(const uint4*)(wSrc[r] + kt);
    // B: async direct-to-LDS
    #pragma unroll
    for (int r = 0; r < 4; ++r)
      async16(bSrc[r] + kt, (u16*)((char*)ldsB + r*4096 + wid*1024));
    #pragma unroll
    for (int r = 0; r < 4; ++r){
      const u16* q = (const u16*)&qa[r];
      const u16* wv = (const u16*)&wa[r];
      u16 o[8];
      #pragma unroll
      for (int j = 0; j < 8; ++j) o[j] = f2bf(bf2f(q[j]) * bf2f(wv[j]));
      *(uint4*)((char*)ldsA + dOff[r]) = *(const uint4*)o;
    }
    __syncthreads();
    #pragma unroll
    for (int s = 0; s < 2; ++s){
      bf16x8 ar[4], br[4];
      #pragma unroll
      for (int i = 0; i < 4; ++i) ar[i] = *(const bf16x8*)((const char*)ldsA + aOff[s][i]);
      #pragma unroll
      for (int i = 0; i < 4; ++i) br[i] = *(const bf16x8*)((const char*)ldsB + bOff[s][i]);
      #pragma unroll
      for (int i = 0; i < 4; ++i)
        #pragma unroll
        for (int j = 0; j < 4; ++j)
          acc[i][j] = __builtin_amdgcn_mfma_f32_16x16x32_bf16(br[j], ar[i], acc[i][j], 0, 0, 0);
    }
    __syncthreads();
  }

  // epilogue: + bias + resid, LDS bounce -> full-line stores
  u16* eb = ldsA + wid * 1152;          // row stride 72 u16 (144 B)
  const int cb0 = tileN + wnBase;
  #pragma unroll
  for (int i = 0; i < 4; ++i){
    const int row = tileM + wmBase + i*16 + lr;
    #pragma unroll
    for (int j = 0; j < 4; ++j){
      const int cl = j*16 + quad*4;
      const float4 bvv = *(const float4*)(bias0 + cb0 + cl);
      uint2 pr = *(const uint2*)(resid + (size_t)row * 512 + cb0 + cl);
      const u16* rp = (const u16*)&pr;
      u16 o[4];
      #pragma unroll
      for (int r = 0; r < 4; ++r)
        o[r] = f2bf(acc[i][j][r] + ((const float*)&bvv)[r] + bf2f(rp[r]));
      *(uint2*)(eb + lr*72 + cl) = *(const uint2*)o;
    }
    __asm__ volatile("s_waitcnt lgkmcnt(0)" ::: "memory");
    uint4 p0 = *(const uint4*)(eb + lr*72 + quad*16);
    uint4 p1 = *(const uint4*)(eb + lr*72 + quad*16 + 8);
    __asm__ volatile("s_waitcnt lgkmcnt(0)" ::: "memory");
    u16* gp = out0 + (size_t)row * 512 + cb0 + quad*16;
    *(uint4*)gp = p0;
    *(uint4*)(gp + 8) = p1;
  }
}

// ======== 256x256 bf16 MFMA GEMM (R3-verified; EPI 0,2,3) ========
template<int EPI, int KC>
__global__ __launch_bounds__(512, 2)
void gemm256(const u16* __restrict__ A, const u16* __restrict__ Bt,
             const float* __restrict__ bias0, const float* __restrict__ wbias,
             u16* __restrict__ out0, u16* __restrict__ out1, u16* __restrict__ out2,
             const float* __restrict__ bias1, const float* __restrict__ bias2,
             float* __restrict__ outf){
  constexpr int NK = KC / 64;
  __shared__ __align__(16) char smem[65536];  // A0|A1|B0|B1, 16 KiB each

  const int tid  = threadIdx.x;
  const int wid  = tid >> 6;
  const int lane = tid & 63;
  const int quad = lane >> 4;
  const int lr   = lane & 15;
  const int wm   = wid & 1;      // M-wave (2)
  const int wn   = wid >> 1;     // N-wave (4)

  // bijective XCD swizzle + L2 supergroups (4 M-tiles x all N-tiles, M fastest)
  const int nwg = gridDim.x;
  const int wg  = (blockIdx.x & 7) * (nwg >> 3) + (blockIdx.x >> 3);
  const int nNT = nwg >> 7;
  const int sgs = nNT << 2;
  const int sg  = wg / sgs;
  const int r   = wg - sg * sgs;
  const int tileM = (sg*4 + (r & 3)) * 256;
  const int tileN = (r >> 2) * 256;

  const u16* sA[2][2]; const u16* sB[2][2];
  {
    const int off0 = wid*1024 + lane*16;
    #pragma unroll
    for (int rr_ = 0; rr_ < 2; ++rr_){
      const int off = rr_*8192 + off0;
      const int rr  = off >> 7;
      const int g   = (((off >> 4) & 7) ^ (rr & 7)) * 8;
      #pragma unroll
      for (int h = 0; h < 2; ++h){
        sA[h][rr_] = A  + (size_t)(tileM + (rr>>6)*128 + h*64 + (rr&63)) * KC + g;
        sB[h][rr_] = Bt + (size_t)(tileN + (rr>>5)*64  + h*32 + (rr&31)) * KC + g;
      }
    }
  }
  auto stA = [&](int h, int kt){
    char* d = smem + h*16384 + wid*1024;
    async16(sA[h][0] + kt, (u16*)d);
    async16(sA[h][1] + kt, (u16*)(d + 8192));
  };
  auto stB = [&](int h, int kt){
    char* d = smem + 32768 + h*16384 + wid*1024;
    async16(sB[h][0] + kt, (u16*)d);
    async16(sB[h][1] + kt, (u16*)(d + 8192));
  };

  const int cO0  = ((quad)     ^ (lr & 7)) * 16;
  const int cO1  = ((quad ^ 4) ^ (lr & 7)) * 16;
  const int aRow = (wm*64 + lr) * 128;
  const int bRow = (wn*32 + lr) * 128;

  bf16x8 ar[4][2], br0[2][2], br1[2][2];
  f32x4 acc[2][2][4][2] = {};

  auto ldA = [&](int mh){
    #pragma unroll
    for (int i = 0; i < 4; ++i){
      ar[i][0] = *(const bf16x8*)(smem + mh*16384 + aRow + i*2048 + cO0);
      ar[i][1] = *(const bf16x8*)(smem + mh*16384 + aRow + i*2048 + cO1);
    }
  };
  auto ldB = [&](int nh, bf16x8 (&br)[2][2]){
    #pragma unroll
    for (int j = 0; j < 2; ++j){
      br[j][0] = *(const bf16x8*)(smem + 32768 + nh*16384 + bRow + j*2048 + cO0);
      br[j][1] = *(const bf16x8*)(smem + 32768 + nh*16384 + bRow + j*2048 + cO1);
    }
  };
  auto MF = [&](int mh, int nh, bf16x8 (&br)[2][2]){
    __builtin_amdgcn_s_setprio(1);
    #pragma unroll
    for (int i = 0; i < 4; ++i)
      #pragma unroll
      for (int j = 0; j < 2; ++j){
        acc[mh][nh][i][j] = __builtin_amdgcn_mfma_f32_16x16x32_bf16(br[j][0], ar[i][0], acc[mh][nh][i][j], 0, 0, 0);
        acc[mh][nh][i][j] = __builtin_amdgcn_mfma_f32_16x16x32_bf16(br[j][1], ar[i][1], acc[mh][nh][i][j], 0, 0, 0);
      }
    __builtin_amdgcn_s_setprio(0);
  };

  stA(0, 0); stB(0, 0); stB(1, 0); stA(1, 0);
  VMCNT(4);
  BARRIER();

  #pragma unroll 1
  for (int t = 0; t < NK-1; ++t){
    const int kt = (t+1)*64;
    ldA(0); ldB(0, br0);
    BARRIER(); LGKM0();
    MF(0, 0, br0);
    VMCNT(2);
    BARRIER();
    ldB(1, br1);
    stA(0, kt); stB(0, kt);
    BARRIER(); LGKM0();
    MF(0, 1, br1);
    VMCNT(4);
    BARRIER();
    ldA(1);
    stB(1, kt);
    BARRIER(); LGKM0();
    MF(1, 1, br1);
    BARRIER();
    stA(1, kt);
    MF(1, 0, br0);
    VMCNT(4);
    BARRIER();
  }
  ldA(0); ldB(0, br0);
  BARRIER(); LGKM0();
  MF(0, 0, br0);
  VMCNT(2);
  BARRIER();
  ldB(1, br1);
  BARRIER(); LGKM0();
  MF(0, 1, br1);
  VMCNT(0);
  BARRIER();
  ldA(1);
  BARRIER(); LGKM0();
  MF(1, 1, br1);
  BARRIER();
  MF(1, 0, br0);

  // ---- epilogue ----
  if (EPI == 3){
    #pragma unroll
    for (int mh = 0; mh < 2; ++mh)
    #pragma unroll
    for (int i = 0; i < 4; ++i){
      const int row = tileM + wm*128 + mh*64 + i*16 + lr;
      #pragma unroll
      for (int nh = 0; nh < 2; ++nh)
      #pragma unroll
      for (int j = 0; j < 2; ++j){
        const int colb = tileN + wn*64 + nh*32 + j*16 + quad*4;
        const float4 bvv = *(const float4*)(bias0 + colb);
        float4 o;
        #pragma unroll
        for (int r_ = 0; r_ < 4; ++r_)
          ((float*)&o)[r_] = 2.0f * (acc[mh][nh][i][j][r_] + ((const float*)&bvv)[r_]);
        *(float4*)(outf + (size_t)row * 512 + colb) = o;
      }
    }
    return;
  }

  char* eb = smem + wid * 2304;
  const int mat = (EPI == 0) ? (tileN >> 10) : 0;   // 0:Q 1:K 2:V
  const float* biasP = bias0;
  u16* outP = out0;
  int cb0 = tileN + wn*64;
  if (EPI == 0){
    biasP = (mat==0) ? bias0 : (mat==1) ? bias1 : bias2;
    outP  = (mat==0) ? out0  : (mat==1) ? out1  : out2;
    cb0   = (tileN & 1023) + wn*64;
  }

  #pragma unroll
  for (int mh = 0; mh < 2; ++mh)
  #pragma unroll
  for (int i = 0; i < 4; ++i){
    const int row = tileM + wm*128 + mh*64 + i*16 + lr;
    #pragma unroll
    for (int nh = 0; nh < 2; ++nh)
    #pragma unroll
    for (int j = 0; j < 2; ++j){
      const int cl = (nh*2 + j)*16 + quad*4;
      const float4 bvv = *(const float4*)(biasP + cb0 + cl);
      u16 o[4];
      if (EPI == 0){
        float4 wbv = {0,0,0,0};
        if (mat == 1) wbv = *(const float4*)(wbias + cb0 + cl);
        #pragma unroll
        for (int r_ = 0; r_ < 4; ++r_){
          float v = acc[mh][nh][i][j][r_] + ((const float*)&bvv)[r_];
          if (mat == 0)      v = fast_rcp(1.0f + __expf(-v));
          else if (mat == 1) v = __expf(v + ((const float*)&wbv)[r_]);
          o[r_] = f2bf(v);
        }
      } else {
        #pragma unroll
        for (int r_ = 0; r_ < 4; ++r_){
          float v  = acc[mh][nh][i][j][r_] + ((const float*)&bvv)[r_];
          float u2 = 2.0f * v * (0.7978845608f + 0.0356774081f * v * v);
          float tg = 1.0f - 2.0f * fast_rcp(1.0f + __expf(u2));
          o[r_] = f2bf(0.5f * v * (1.0f + tg));
        }
      }
      *(uint2*)(eb + lr*144 + cl*2) = *(const uint2*)o;
    }
    __asm__ volatile("s_waitcnt lgkmcnt(0)" ::: "memory");
    uint4 p0 = *(const uint4*)(eb + lr*144 + quad*32);
    uint4 p1 = *(const uint4*)(eb + lr*144 + quad*32 + 16);
    __asm__ volatile("s_waitcnt lgkmcnt(0)" ::: "memory");
    u16* gp = outP + (size_t)row * 1024 + cb0 + quad*16;
    *(uint4*)gp = p0;
    *(uint4*)(gp + 8) = p1;
  }
}

extern "C" void kernel_launch(void* const* d_in, const int* in_sizes, int n_in,
                              void* d_out, int out_size, void* d_ws, size_t ws_size,
                              hipStream_t stream) {
  const float* x     = (const float*)d_in[0];
  const float* gamma = (const float*)d_in[1];
  const float* beta  = (const float*)d_in[2];
  const float* Wq    = (const float*)d_in[3];
  const float* bq    = (const float*)d_in[4];
  const float* Wk    = (const float*)d_in[5];
  const float* bk    = (const float*)d_in[6];
  const float* Wv    = (const float*)d_in[7];
  const float* bv    = (const float*)d_in[8];
  const float* wbias = (const float*)d_in[9];
  const float* Wo    = (const float*)d_in[10];
  const float* bo    = (const float*)d_in[11];
  const float* W1    = (const float*)d_in[12];
  const float* b1    = (const float*)d_in[13];
  const float* W2    = (const float*)d_in[14];
  const float* b2    = (const float*)d_in[15];
  float* out = (float*)d_out;

  char* w = (char*)d_ws;
  const size_t MB = 1ull << 20;
  u16* WqkvT = (u16*)(w + 0*MB);      // [3072][512]  (WqT | WkT | WvT)
  u16* WoT   = (u16*)(w + 3*MB);      // [512][1024]
  u16* W1T   = (u16*)(w + 4*MB);      // [1024][512]
  u16* W2T   = (u16*)(w + 5*MB);      // [512][1024]
  u16* x1b   = (u16*)(w + 6*MB);      // [32768][512]
  u16* Qs    = (u16*)(w + 38*MB);     // [32768][1024]  sigmoid(Q)
  u16* Nu    = (u16*)(w + 102*MB);    // [32768][1024]  exp(K+wbias)
  u16* Vb    = (u16*)(w + 166*MB);    // [32768][1024]  V
  u16* Wt    = Nu;                    // [4096][1024] weighted, in-place over Nu
  u16* x2b   = Vb;                    // reuse (V consumed by aft_weighted)
  u16* x3b   = (u16*)(w + 198*MB);
  u16* hb    = Qs;                    // reuse (Qs consumed by gemm128_yt)

  // fused: 6 weight transposes (z=0..5) + LN1 (z=6..13), one dispatch
  prep_fused<<<dim3(32, 32, 14), dim3(32, 8), 0, stream>>>(
      Wq, Wk, Wv, Wo, W1, W2,
      WqkvT, WqkvT + 1024*512, WqkvT + 2*1024*512, WoT, W1T, W2T,
      x, gamma, beta, x1b);

  // QKV: [32768,512] @ [3072,512]^T ; 128 M-tiles x 12 N-tiles (256^2, R3 schedule)
  gemm256<0, 512><<<1536, 512, 0, stream>>>(x1b, WqkvT,
      bq, wbias, Qs, Nu, Vb, bk, bv, nullptr);

  // AFT reduction only: weighted[t,h], in-place over Nu
  aft_weighted<<<2048, 256, 0, stream>>>(Nu, Vb, Wt);

  // attn out, FUSED Yt: x2 = (Qs .* Wt) @ WoT^T + bo + x1   (128^2, 3 blocks/CU)
  gemm128_yt<<<1024, 256, 0, stream>>>(Qs, WoT, 4, Wt, bo, x2b, x1b);

  ln_kernel<true><<<8192, 256, 0, stream>>>(x2b, gamma, beta, x3b);

  // mlp1: [32768,512] @ [1024,512]^T ; 128 x 4 (256^2)
  gemm256<2, 512><<<512, 512, 0, stream>>>(x3b, W1T,
      b1, nullptr, hb, nullptr, nullptr, nullptr, nullptr, nullptr);

  // mlp2: [32768,1024] @ [512,1024]^T ; 128 x 2 (256^2)
  gemm256<3, 1024><<<256, 512, 0, stream>>>(hb, W2T,
      b2, nullptr, nullptr, nullptr, nullptr, nullptr, nullptr, out);
}